// Round 1
// baseline (29750.357 us; speedup 1.0000x reference)
//
#include <hip/hip_runtime.h>
#include <cstdint>
#include <cstddef>

#define L_ 128
#define B_ 32
#define E_ 512
#define H_ 512
#define H2_ 1024
#define V_ 32000
#define SOS_ 65

typedef __attribute__((ext_vector_type(8))) short bf8;
typedef __attribute__((ext_vector_type(4))) float f4;

__device__ __forceinline__ short bf1(float x){
  union { float f; unsigned u; } c; c.f = x;
  return (short)((c.u + 0x8000u) >> 16);
}
__device__ __forceinline__ bf8 fragf(const float* p){
  f4 a = ((const f4*)p)[0], b = ((const f4*)p)[1];
  bf8 r;
  r[0]=bf1(a[0]); r[1]=bf1(a[1]); r[2]=bf1(a[2]); r[3]=bf1(a[3]);
  r[4]=bf1(b[0]); r[5]=bf1(b[1]); r[6]=bf1(b[2]); r[7]=bf1(b[3]);
  return r;
}
__device__ __forceinline__ float sigf(float x){ return 1.0f/(1.0f + __expf(-x)); }
__device__ __forceinline__ float tanh_(float x){ return 1.0f - 2.0f/(__expf(2.0f*x)+1.0f); }
__device__ __forceinline__ f4 mfma16(bf8 a, bf8 b, f4 c){
  return __builtin_amdgcn_mfma_f32_16x16x32_bf16(a, b, c, 0, 0, 0);
}
__device__ __forceinline__ void comb3(float& M, float& S, int& I,
                                      float m2, float s2, int i2){
  if (m2 > M) { S = s2 + S*__expf(M - m2); M = m2; I = i2; }
  else { S += s2*__expf(m2 - M); if (m2 == M && i2 < I) I = i2; }
}

// ---- device-wide generation barrier (grid co-resident by construction) ----
// Arrival fetch_add is ACQ_REL (release: drains this block's stores, wbL2;
// acquire chains RMW releases). Spin polls RELAXED (no per-poll L2 inv);
// one ACQUIRE load on exit invalidates L1/L2 for fresh reads.
__device__ __forceinline__ void gbar(int* cnt, int* gen, int nblk){
  __syncthreads();
  if (threadIdx.x == 0){
    int g = __hip_atomic_load(gen, __ATOMIC_RELAXED, __HIP_MEMORY_SCOPE_AGENT);
    int a = __hip_atomic_fetch_add(cnt, 1, __ATOMIC_ACQ_REL, __HIP_MEMORY_SCOPE_AGENT);
    if (a == nblk - 1){
      __hip_atomic_store(cnt, 0, __ATOMIC_RELAXED, __HIP_MEMORY_SCOPE_AGENT);
      __hip_atomic_fetch_add(gen, 1, __ATOMIC_ACQ_REL, __HIP_MEMORY_SCOPE_AGENT);
    } else {
      while (__hip_atomic_load(gen, __ATOMIC_RELAXED, __HIP_MEMORY_SCOPE_AGENT) == g)
        __builtin_amdgcn_s_sleep(2);
    }
    (void)__hip_atomic_load(gen, __ATOMIC_ACQUIRE, __HIP_MEMORY_SCOPE_AGENT);
  }
  __syncthreads();
}

// ---------------- init ----------------
__global__ __launch_bounds__(256) void k_init(float* __restrict__ ws,
                                              int* __restrict__ inp,
                                              float* __restrict__ loss,
                                              int* __restrict__ cnt,
                                              int* __restrict__ gen)
{
  int gid = blockIdx.x*256 + threadIdx.x;        // < 98304
  ws[gid] = 0.f;                                  // cf,cb,c_d,h_d
  ws[262144 + gid] = 0.f;                         // h_enc_bf + h_dec_bf (both bufs)
  if (gid < 32) inp[gid] = SOS_;
  if (gid == 0) { *loss = 0.f; *cnt = 0; *gen = 0; }
}

// ---------------- one-shot bf16 pre-pack of all GEMM B-operands ----------
// frag8 segments (within pack region, units of 8 shorts):
// [0,131072) Whh_f | [131072,262144) Whh_b | [262144,524288) W_comb |
// [524288,1048576) Wih_d | [1048576,1572864) Whh_d | [1572864,5668864) W_out
__global__ __launch_bounds__(256) void k_packall(
    const float* __restrict__ Whh_f, const float* __restrict__ Whh_b,
    const float* __restrict__ W_comb, const float* __restrict__ Wih_d,
    const float* __restrict__ Whh_d, const float* __restrict__ W_out,
    short* __restrict__ pk, long n8)
{
  long gid = (long)blockIdx.x*256 + threadIdx.x;
  if (gid >= n8) return;
  const float* src; short* dst; long idx;
  if      (gid < 131072)  { src = Whh_f;  dst = pk;            idx = gid; }
  else if (gid < 262144)  { src = Whh_b;  dst = pk + 1048576;  idx = gid - 131072; }
  else if (gid < 524288)  { src = W_comb; dst = pk + 2097152;  idx = gid - 262144; }
  else if (gid < 1048576) { src = Wih_d;  dst = pk + 4194304;  idx = gid - 524288; }
  else if (gid < 1572864) { src = Whh_d;  dst = pk + 8388608;  idx = gid - 1048576; }
  else                    { src = W_out;  dst = pk + 12582912; idx = gid - 1572864; }
  ((bf8*)dst)[idx] = fragf(src + idx*8);
}

// ---------------- persistent encoder: 64 blocks, 128 steps, 1 gbar/step ----
// block = (dir, j-chunk of 16): computes all 4 gates for its j's (GEMM over
// full K=1024) then the LSTM cell block-locally. h bf16 ping-pong by t-parity.
template<bool PKW>
__global__ __launch_bounds__(256, 2) void k_encoder(
    const int* __restrict__ x, const float* __restrict__ emb_enc,
    const float* __restrict__ Wih_f, const float* __restrict__ Wih_b,
    const float* __restrict__ WhhF_f32, const float* __restrict__ WhhB_f32,
    const short* __restrict__ WhhF_bf, const short* __restrict__ WhhB_bf,
    const float* __restrict__ bih_f, const float* __restrict__ bhh_f,
    const float* __restrict__ bih_b, const float* __restrict__ bhh_b,
    float* __restrict__ cf, float* __restrict__ cb,
    short* __restrict__ hbuf,   // [2 bufs][2 dirs][32][512]
    float* __restrict__ EO,
    int* __restrict__ cnt, int* __restrict__ gen)
{
  __shared__ __align__(16) float G[64][33];
  const int tid = threadIdx.x, wave = tid >> 6, lane = tid & 63;
  const int q = lane >> 4, col = lane & 15, kq = q*8;
  const int bid = blockIdx.x;
  const int dir = bid >> 5, j0 = (bid & 31) * 16;
  const float* Wih  = dir ? Wih_b    : Wih_f;
  const float* Whhf = dir ? WhhB_f32 : WhhF_f32;
  const short* Whhs = dir ? WhhB_bf  : WhhF_bf;
  const float* bi = dir ? bih_b : bih_f;
  const float* bh = dir ? bhh_b : bhh_f;
  float* C = dir ? cb : cf;
  const int n_glob = wave*512 + j0 + col;   // weight row: gate=wave, j=j0+col

  for (int t = 0; t < L_; ++t){
    const short* hcur = hbuf + (size_t)(((t    & 1)*2 + dir))*16384;
    short*       hnxt = hbuf + (size_t)((((t+1)& 1)*2 + dir))*16384;
    f4 acc0 = {0.f,0.f,0.f,0.f}, acc1 = {0.f,0.f,0.f,0.f};
    { // ih part, K = 0..511 (embedding gather, fp32 -> bf16 at use)
      const float* a0 = emb_enc + (size_t)x[col*L_ + t]*E_ + kq;
      const float* a1 = emb_enc + (size_t)x[(16+col)*L_ + t]*E_ + kq;
      const float* bp = Wih + (size_t)n_glob*512 + kq;
#pragma unroll 4
      for (int i = 0; i < 16; ++i){
        bf8 bb = fragf(bp + i*32);
        acc0 = mfma16(fragf(a0 + i*32), bb, acc0);
        acc1 = mfma16(fragf(a1 + i*32), bb, acc1);
      }
    }
    { // hh part, K = 512..1023 (bf16 A, packed bf16 B when available)
      const short* a0 = hcur + col*512 + kq;
      const short* a1 = hcur + (16+col)*512 + kq;
      const float* bpf = Whhf + (size_t)n_glob*512 + kq;
      const short* bps = Whhs + (size_t)n_glob*512 + kq;
#pragma unroll 4
      for (int i = 0; i < 16; ++i){
        bf8 bb = PKW ? *(const bf8*)(bps + i*32) : fragf(bpf + i*32);
        acc0 = mfma16(*(const bf8*)(a0 + i*32), bb, acc0);
        acc1 = mfma16(*(const bf8*)(a1 + i*32), bb, acc1);
      }
    }
    const int n_loc = wave*16 + col;
#pragma unroll
    for (int r = 0; r < 4; ++r){
      G[n_loc][4*q + r]      = acc0[r];
      G[n_loc][16 + 4*q + r] = acc1[r];
    }
    __syncthreads();
#pragma unroll
    for (int s = 0; s < 2; ++s){
      const int cid = tid + s*256;
      const int b = cid & 31, jj = cid >> 5;
      const int j = j0 + jj;
      float g[4];
#pragma unroll
      for (int gt = 0; gt < 4; ++gt){
        const int n = gt*512 + j;
        g[gt] = G[gt*16 + jj][b] + bi[n] + bh[n];
      }
      float cp = C[b*512 + j];
      float cn = sigf(g[1])*cp + sigf(g[0])*tanh_(g[2]);
      float hn = sigf(g[3])*tanh_(cn);
      C[b*512 + j] = cn;
      hnxt[b*512 + j] = bf1(hn);
      if (b == 0) EO[t*H2_ + dir*512 + j] = hn;   // faithful source-bug broadcast
    }
    gbar(cnt, gen, 64);    // entry __syncthreads also guards G reuse
  }
}

// ---------------- decoder phase helpers ----------------
__device__ __forceinline__ void reduce_body(
    int b, int tid, const float* __restrict__ pmax,
    const float* __restrict__ psum, const int* __restrict__ pidx,
    const float* __restrict__ ptgt, float* __restrict__ loss,
    int* __restrict__ inp, float* SH, int* srow)
{
  float M = -3.4e38f, S = 0.f; int I = 0x7fffffff;
  for (int tl = tid; tl < 500; tl += 256)
    comb3(M, S, I, pmax[tl*32 + b], psum[tl*32 + b], pidx[tl*32 + b]);
#pragma unroll
  for (int msk = 1; msk < 64; msk <<= 1){
    float m2 = __shfl_xor(M, msk), s2 = __shfl_xor(S, msk);
    int i2 = __shfl_xor(I, msk);
    comb3(M, S, I, m2, s2, i2);
  }
  float* sm = SH; float* ss = SH + 8; int* si = (int*)(SH + 16);
  if ((tid & 63) == 0){ sm[tid>>6] = M; ss[tid>>6] = S; si[tid>>6] = I; }
  __syncthreads();
  if (tid == 0){
    M = sm[0]; S = ss[0]; I = si[0];
#pragma unroll
    for (int w = 1; w < 4; ++w) comb3(M, S, I, sm[w], ss[w], si[w]);
    atomicAdd(loss, (M + __logf(S) - ptgt[b]) * (1.0f/32.0f));
    inp[b] = I;
    *srow = I;
  }
}

__device__ __forceinline__ void attn_body(
    int b, int tid, int row,
    const float* __restrict__ emb_dec, const float* __restrict__ h_d,
    const float* __restrict__ W_attn, const float* __restrict__ b_attn,
    const float* __restrict__ EO, float* __restrict__ ctx, float* SH)
{
  float* X = SH; float* sc = SH + 2048; float* red = SH + 2176;
  ((f4*)X)[tid]          = ((const f4*)(emb_dec + (size_t)row*H2_))[tid];
  ((f4*)(X + 1024))[tid] = ((const f4*)(h_d + (size_t)b*H2_))[tid];
  __syncthreads();
  const int lg = tid >> 4, kl = tid & 15;
#pragma unroll
  for (int lr = 0; lr < 8; ++lr){
    const int l = lr*16 + lg;
    const float* w = W_attn + (size_t)l*2048;
    float s = 0.f;
    for (int kk = kl*4; kk < 2048; kk += 64){
      f4 wv = *(const f4*)(w + kk);
      f4 xv = *(const f4*)(X + kk);
      s += wv[0]*xv[0] + wv[1]*xv[1] + wv[2]*xv[2] + wv[3]*xv[3];
    }
#pragma unroll
    for (int msk = 1; msk < 16; msk <<= 1) s += __shfl_xor(s, msk);
    if (kl == 0) sc[l] = s + b_attn[l];
  }
  __syncthreads();
  const float v = sc[tid & 127];
  float m_ = v;
#pragma unroll
  for (int msk = 1; msk < 64; msk <<= 1) m_ = fmaxf(m_, __shfl_xor(m_, msk));
  if ((tid & 63) == 0) red[tid >> 6] = m_;
  __syncthreads();
  const float M = fmaxf(fmaxf(red[0], red[1]), fmaxf(red[2], red[3]));
  const float e_ = __expf(v - M);
  float s_ = e_;
#pragma unroll
  for (int msk = 1; msk < 64; msk <<= 1) s_ += __shfl_xor(s_, msk);
  if ((tid & 63) == 0) red[4 + (tid >> 6)] = s_;
  __syncthreads();
  const float S = red[4] + red[5];
  if (tid < 128) sc[tid] = e_ / S;
  __syncthreads();
  const int d0 = tid*4;
  f4 a = {0.f,0.f,0.f,0.f};
  for (int l = 0; l < 128; ++l){
    const float wgt = sc[l];
    const f4 ev = *(const f4*)(EO + (size_t)l*H2_ + d0);
    a[0] += wgt*ev[0]; a[1] += wgt*ev[1]; a[2] += wgt*ev[2]; a[3] += wgt*ev[3];
  }
  *(f4*)(ctx + (size_t)b*H2_ + d0) = a;
}

// ---------------- persistent decoder: 256 blocks, 128 steps, 4 gbar/step ----
template<bool PKW, bool PKOUT>
__global__ __launch_bounds__(256, 2) void k_decoder(
    const int* __restrict__ target, const float* __restrict__ emb_dec,
    const float* __restrict__ W_attn, const float* __restrict__ b_attn,
    const float* __restrict__ Wcomb_f32, const short* __restrict__ Wcomb_bf,
    const float* __restrict__ b_comb,
    const float* __restrict__ WihD_f32, const short* __restrict__ WihD_bf,
    const float* __restrict__ WhhD_f32, const short* __restrict__ WhhD_bf,
    const float* __restrict__ bih_d, const float* __restrict__ bhh_d,
    const float* __restrict__ Wout_f32, const short* __restrict__ Wout_bf,
    const float* __restrict__ b_out, const float* __restrict__ EO,
    float* __restrict__ h_d, float* __restrict__ c_d,
    short* __restrict__ hdbuf,    // [2 bufs][32][1024] bf16
    short* __restrict__ combb,    // [32][1024] bf16 (post-relu comb)
    float* __restrict__ ctx,
    float* __restrict__ pmax, float* __restrict__ psum,
    int* __restrict__ pidx, float* __restrict__ ptgt,
    float* __restrict__ loss, int* __restrict__ inp,
    int* __restrict__ cnt, int* __restrict__ gen,
    float* __restrict__ out)
{
  __shared__ __align__(16) float SH[2184];
  __shared__ int s_row;
  const int tid = threadIdx.x, wave = tid >> 6, lane = tid & 63;
  const int q = lane >> 4, col = lane & 15, kq = q*8;
  const int bid = blockIdx.x;

  for (int t = 0; t < L_; ++t){
    const short* hcur = hdbuf + (size_t)(t & 1)*32768;
    short*       hnxt = hdbuf + (size_t)((t+1) & 1)*32768;

    // ---- phase 1 (blocks 0..31): finalize step t-1 (nll + argmax) + attn ----
    if (bid < 32){
      const int b = bid;
      if (t > 0)
        reduce_body(b, tid, pmax, psum, pidx, ptgt, loss, inp, SH, &s_row);
      __syncthreads();
      const int row = (t > 0) ? s_row : inp[b];
      attn_body(b, tid, row, emb_dec, h_d, W_attn, b_attn, EO, ctx, SH);
    }
    gbar(cnt, gen, 256);

    // ---- phase 2 (blocks 0..15): comb = relu(concat(e,ctx)@W_comb^T+b) -> bf16
    if (bid < 16){
      const int n = bid*64 + wave*16 + col;
      const int r0 = inp[col], r1 = inp[16+col];
      const float* e0 = emb_dec + (size_t)r0*H2_;
      const float* e1 = emb_dec + (size_t)r1*H2_;
      const float* c0 = ctx + col*H2_;
      const float* c1 = ctx + (16+col)*H2_;
      const float* bpf = Wcomb_f32 + (size_t)n*2048;
      const short* bps = Wcomb_bf  + (size_t)n*2048;
      f4 acc0 = {0.f,0.f,0.f,0.f}, acc1 = {0.f,0.f,0.f,0.f};
#pragma unroll 4
      for (int i = 0; i < 32; ++i){
        const int k = i*32 + kq;
        bf8 bb = PKW ? *(const bf8*)(bps + k) : fragf(bpf + k);
        acc0 = mfma16(fragf(e0 + k), bb, acc0);
        acc1 = mfma16(fragf(e1 + k), bb, acc1);
      }
#pragma unroll 4
      for (int i = 0; i < 32; ++i){
        const int k = i*32 + kq;
        bf8 bb = PKW ? *(const bf8*)(bps + 1024 + k) : fragf(bpf + 1024 + k);
        acc0 = mfma16(fragf(c0 + k), bb, acc0);
        acc1 = mfma16(fragf(c1 + k), bb, acc1);
      }
      const float bias = b_comb[n];
#pragma unroll
      for (int r = 0; r < 4; ++r){
        combb[(4*q + r)*H2_ + n]      = bf1(fmaxf(acc0[r] + bias, 0.f));
        combb[(16 + 4*q + r)*H2_ + n] = bf1(fmaxf(acc1[r] + bias, 0.f));
      }
    }
    gbar(cnt, gen, 256);

    // ---- phase 3 (blocks 0..63): LSTM gates GEMM (K=2048) + cell, fused ----
    if (bid < 64){
      const int j0 = bid*16;
      const int n_glob = wave*1024 + j0 + col;   // gate=wave, j=j0+col
      const short* a0c = combb + col*H2_ + kq;
      const short* a1c = combb + (16+col)*H2_ + kq;
      const short* a0h = hcur + col*H2_ + kq;
      const short* a1h = hcur + (16+col)*H2_ + kq;
      const float* bif = WihD_f32 + (size_t)n_glob*H2_ + kq;
      const short* bis = WihD_bf  + (size_t)n_glob*H2_ + kq;
      const float* bhf = WhhD_f32 + (size_t)n_glob*H2_ + kq;
      const short* bhs = WhhD_bf  + (size_t)n_glob*H2_ + kq;
      f4 acc0 = {0.f,0.f,0.f,0.f}, acc1 = {0.f,0.f,0.f,0.f};
#pragma unroll 4
      for (int i = 0; i < 32; ++i){
        bf8 bb = PKW ? *(const bf8*)(bis + i*32) : fragf(bif + i*32);
        acc0 = mfma16(*(const bf8*)(a0c + i*32), bb, acc0);
        acc1 = mfma16(*(const bf8*)(a1c + i*32), bb, acc1);
      }
#pragma unroll 4
      for (int i = 0; i < 32; ++i){
        bf8 bb = PKW ? *(const bf8*)(bhs + i*32) : fragf(bhf + i*32);
        acc0 = mfma16(*(const bf8*)(a0h + i*32), bb, acc0);
        acc1 = mfma16(*(const bf8*)(a1h + i*32), bb, acc1);
      }
      float (*G)[33] = (float(*)[33])SH;
      const int n_loc = wave*16 + col;
#pragma unroll
      for (int r = 0; r < 4; ++r){
        G[n_loc][4*q + r]      = acc0[r];
        G[n_loc][16 + 4*q + r] = acc1[r];
      }
      __syncthreads();
#pragma unroll
      for (int s = 0; s < 2; ++s){
        const int cid = tid + s*256;
        const int b = cid & 31, jj = cid >> 5;
        const int j = j0 + jj;
        float g[4];
#pragma unroll
        for (int gt = 0; gt < 4; ++gt){
          const int n = gt*1024 + j;
          g[gt] = G[gt*16 + jj][b] + bih_d[n] + bhh_d[n];
        }
        float cp = c_d[b*H2_ + j];
        float cn = sigf(g[1])*cp + sigf(g[0])*tanh_(g[2]);
        float hn = sigf(g[3])*tanh_(cn);
        c_d[b*H2_ + j] = cn;
        h_d[b*H2_ + j] = hn;
        hnxt[b*H2_ + j] = bf1(hn);
      }
    }
    gbar(cnt, gen, 256);

    // ---- phase 4 (all blocks): logits GEMM + per-tile online softmax ----
    for (int nt = bid; nt < 500; nt += 256){
      __syncthreads();
      float (*lmax)[32] = (float(*)[32])SH;
      float (*lsum)[32] = (float(*)[32])(SH + 128);
      int   (*lidx)[32] = (int(*)[32])(SH + 256);
      const int n = nt*64 + wave*16 + col;
      const short* a0 = hnxt + col*H2_ + kq;
      const short* a1 = hnxt + (16+col)*H2_ + kq;
      f4 acc[2];
      acc[0] = (f4){0.f,0.f,0.f,0.f};
      acc[1] = (f4){0.f,0.f,0.f,0.f};
      if (PKOUT){
        const short* bp = Wout_bf + (size_t)n*H2_ + kq;
#pragma unroll 8
        for (int i = 0; i < 32; ++i){
          bf8 bb = *(const bf8*)(bp + i*32);
          acc[0] = mfma16(*(const bf8*)(a0 + i*32), bb, acc[0]);
          acc[1] = mfma16(*(const bf8*)(a1 + i*32), bb, acc[1]);
        }
      } else {
        const float* bp = Wout_f32 + (size_t)n*H2_ + kq;
#pragma unroll 4
        for (int i = 0; i < 32; ++i){
          bf8 bb = fragf(bp + i*32);
          acc[0] = mfma16(*(const bf8*)(a0 + i*32), bb, acc[0]);
          acc[1] = mfma16(*(const bf8*)(a1 + i*32), bb, acc[1]);
        }
      }
      const float bias = b_out[n];
#pragma unroll
      for (int mt = 0; mt < 2; ++mt){
        float val[4], mv[4]; int mi[4];
#pragma unroll
        for (int r = 0; r < 4; ++r){
          val[r] = acc[mt][r] + bias;
          int b_ = mt*16 + 4*q + r;
          if (target[b_*L_ + t] == n) ptgt[b_] = val[r];
          mv[r] = val[r]; mi[r] = n;
        }
#pragma unroll
        for (int msk = 1; msk < 16; msk <<= 1){
#pragma unroll
          for (int r = 0; r < 4; ++r){
            float ov = __shfl_xor(mv[r], msk);
            int oi = __shfl_xor(mi[r], msk);
            if (ov > mv[r] || (ov == mv[r] && oi < mi[r])) { mv[r] = ov; mi[r] = oi; }
          }
        }
        float sv[4];
#pragma unroll
        for (int r = 0; r < 4; ++r) sv[r] = __expf(val[r] - mv[r]);
#pragma unroll
        for (int msk = 1; msk < 16; msk <<= 1){
#pragma unroll
          for (int r = 0; r < 4; ++r) sv[r] += __shfl_xor(sv[r], msk);
        }
        if (col == 0){
#pragma unroll
          for (int r = 0; r < 4; ++r){
            int b_ = mt*16 + 4*q + r;
            lmax[wave][b_] = mv[r]; lsum[wave][b_] = sv[r]; lidx[wave][b_] = mi[r];
          }
        }
      }
      __syncthreads();
      if (tid < 32){
        float M = lmax[0][tid], S = lsum[0][tid]; int I = lidx[0][tid];
#pragma unroll
        for (int w = 1; w < 4; ++w)
          comb3(M, S, I, lmax[w][tid], lsum[w][tid], lidx[w][tid]);
        pmax[nt*32 + tid] = M; psum[nt*32 + tid] = S; pidx[nt*32 + tid] = I;
      }
    }
    gbar(cnt, gen, 256);
  }

  // final nll/argmax for t = 127, then emit outputs
  if (bid < 32)
    reduce_body(bid, tid, pmax, psum, pidx, ptgt, loss, inp, SH, &s_row);
  gbar(cnt, gen, 256);
  if (bid == 0 && tid == 0){
    out[0] = *loss;
    out[1] = *loss * (1.0f/128.0f);
  }
}

// ---------------- host ----------------
extern "C" void kernel_launch(void* const* d_in, const int* in_sizes, int n_in,
                              void* d_out, int out_size, void* d_ws, size_t ws_size,
                              hipStream_t stream)
{
  const int*   x       = (const int*)d_in[0];
  const int*   target  = (const int*)d_in[1];
  const float* emb_enc = (const float*)d_in[4];
  const float* Wih_f   = (const float*)d_in[5];
  const float* Whh_f   = (const float*)d_in[6];
  const float* bih_f   = (const float*)d_in[7];
  const float* bhh_f   = (const float*)d_in[8];
  const float* Wih_b   = (const float*)d_in[9];
  const float* Whh_b   = (const float*)d_in[10];
  const float* bih_b   = (const float*)d_in[11];
  const float* bhh_b   = (const float*)d_in[12];
  const float* emb_dec = (const float*)d_in[13];
  const float* W_attn  = (const float*)d_in[14];
  const float* b_attn  = (const float*)d_in[15];
  const float* W_comb  = (const float*)d_in[16];
  const float* b_comb  = (const float*)d_in[17];
  const float* Wih_d   = (const float*)d_in[18];
  const float* Whh_d   = (const float*)d_in[19];
  const float* bih_d   = (const float*)d_in[20];
  const float* bhh_d   = (const float*)d_in[21];
  const float* W_out   = (const float*)d_in[22];
  const float* b_out   = (const float*)d_in[23];

  float* ws = (float*)d_ws;
  // base region (float offsets)
  float* cf     = ws + 0;        // 16384
  float* cb     = ws + 16384;    // 16384
  float* c_d    = ws + 32768;    // 32768
  float* h_d    = ws + 65536;    // 32768
  float* EO     = ws + 98304;    // 131072
  float* ctx    = ws + 229376;   // 32768
  short* h_enc  = (short*)(ws + 262144);  // 2 bufs x 2 dirs x 32 x 512
  short* h_dec  = (short*)(ws + 327680);  // 2 bufs x 32 x 1024
  short* combb  = (short*)(ws + 360448);  // 32 x 1024
  float* pmax   = ws + 376832;   // 500*32
  float* psum   = ws + 392832;
  int*   pidx   = (int*)(ws + 408832);
  float* ptgt   = ws + 424832;   // 32
  float* loss   = ws + 424864;
  int*   inp    = (int*)(ws + 424896);    // 32
  int*   cnt    = (int*)(ws + 424928);
  int*   gen    = (int*)(ws + 424960);

  // pack region at +8 MiB (short offsets within)
  short* pk = (short*)((char*)d_ws + (8u << 20));
  short* WhhF_bf  = pk;                 // 1,048,576 shorts
  short* WhhB_bf  = pk + 1048576;
  short* Wcomb_bf = pk + 2097152;       // 2,097,152
  short* WihD_bf  = pk + 4194304;       // 4,194,304
  short* WhhD_bf  = pk + 8388608;       // 4,194,304
  short* Wout_bf  = pk + 12582912;      // 32,768,000
  const size_t pkw_end   = (size_t)(8u << 20) + 25165824ull;   // 33,554,432
  const size_t pkout_end = pkw_end + 65536000ull;              // 99,090,432
  const bool PKW   = (ws_size >= pkw_end);
  const bool PKOUT = (ws_size >= pkout_end);

  k_init<<<384, 256, 0, stream>>>(ws, inp, loss, cnt, gen);
  if (PKW){
    const long n8 = PKOUT ? 5668864L : 1572864L;
    const int  gp = (int)((n8 + 255) / 256);
    k_packall<<<gp, 256, 0, stream>>>(Whh_f, Whh_b, W_comb, Wih_d, Whh_d,
                                      W_out, pk, n8);
  }

  if (PKW)
    k_encoder<true><<<64, 256, 0, stream>>>(
        x, emb_enc, Wih_f, Wih_b, Whh_f, Whh_b, WhhF_bf, WhhB_bf,
        bih_f, bhh_f, bih_b, bhh_b, cf, cb, h_enc, EO, cnt, gen);
  else
    k_encoder<false><<<64, 256, 0, stream>>>(
        x, emb_enc, Wih_f, Wih_b, Whh_f, Whh_b, WhhF_bf, WhhB_bf,
        bih_f, bhh_f, bih_b, bhh_b, cf, cb, h_enc, EO, cnt, gen);

  if (PKOUT)
    k_decoder<true, true><<<256, 256, 0, stream>>>(
        target, emb_dec, W_attn, b_attn, W_comb, Wcomb_bf, b_comb,
        Wih_d, WihD_bf, Whh_d, WhhD_bf, bih_d, bhh_d, W_out, Wout_bf, b_out,
        EO, h_d, c_d, h_dec, combb, ctx, pmax, psum, pidx, ptgt,
        loss, inp, cnt, gen, (float*)d_out);
  else if (PKW)
    k_decoder<true, false><<<256, 256, 0, stream>>>(
        target, emb_dec, W_attn, b_attn, W_comb, Wcomb_bf, b_comb,
        Wih_d, WihD_bf, Whh_d, WhhD_bf, bih_d, bhh_d, W_out, Wout_bf, b_out,
        EO, h_d, c_d, h_dec, combb, ctx, pmax, psum, pidx, ptgt,
        loss, inp, cnt, gen, (float*)d_out);
  else
    k_decoder<false, false><<<256, 256, 0, stream>>>(
        target, emb_dec, W_attn, b_attn, W_comb, Wcomb_bf, b_comb,
        Wih_d, WihD_bf, Whh_d, WhhD_bf, bih_d, bhh_d, W_out, Wout_bf, b_out,
        EO, h_d, c_d, h_dec, combb, ctx, pmax, psum, pidx, ptgt,
        loss, inp, cnt, gen, (float*)d_out);
}

// Round 3
// 28857.791 us; speedup vs baseline: 1.0309x; 1.0309x over previous
//
#include <hip/hip_runtime.h>
#include <cstdint>
#include <cstddef>

#define L_ 128
#define B_ 32
#define E_ 512
#define H_ 512
#define H2_ 1024
#define V_ 32000
#define SOS_ 65
#define SCOPE __HIP_MEMORY_SCOPE_AGENT

typedef __attribute__((ext_vector_type(8))) short bf8;
typedef __attribute__((ext_vector_type(4))) float f4;

__device__ __forceinline__ short bf1(float x){
  union { float f; unsigned u; } c; c.f = x;
  return (short)((c.u + 0x8000u) >> 16);
}
__device__ __forceinline__ bf8 fragf(const float* p){
  f4 a = ((const f4*)p)[0], b = ((const f4*)p)[1];
  bf8 r;
  r[0]=bf1(a[0]); r[1]=bf1(a[1]); r[2]=bf1(a[2]); r[3]=bf1(a[3]);
  r[4]=bf1(b[0]); r[5]=bf1(b[1]); r[6]=bf1(b[2]); r[7]=bf1(b[3]);
  return r;
}
__device__ __forceinline__ float sigf(float x){ return 1.0f/(1.0f + __expf(-x)); }
__device__ __forceinline__ float tanh_(float x){ return 1.0f - 2.0f/(__expf(2.0f*x)+1.0f); }
__device__ __forceinline__ f4 mfma16(bf8 a, bf8 b, f4 c){
  return __builtin_amdgcn_mfma_f32_16x16x32_bf16(a, b, c, 0, 0, 0);
}
__device__ __forceinline__ void comb3(float& M, float& S, int& I,
                                      float m2, float s2, int i2){
  if (m2 > M) { S = s2 + S*__expf(M - m2); M = m2; I = i2; }
  else { S += s2*__expf(m2 - M); if (m2 == M && i2 < I) I = i2; }
}

// ---- device-wide flag barrier (no contended RMW) ----
// Each non-master block release-stores its own flag (128B-strided).
// Master (block 0) polls all flags in parallel (1 thread per flag), then
// release-stores gen = token. Everyone acquire-loads gen on exit (same
// acquire-invalidate semantics as the round-1 proven-correct barrier).
// Tokens are monotonic per kernel run -> no flag resets, no ABA.
__device__ __forceinline__ void gbarf(int* flags, int* gen, int bid,
                                      int nblk, int token){
  __syncthreads();   // drains this block's stores before arrival
  if (bid == 0){
    const int tid = threadIdx.x;
    if (tid >= 1 && tid < nblk){
      while (__hip_atomic_load(flags + tid*32, __ATOMIC_RELAXED, SCOPE) < token)
        __builtin_amdgcn_s_sleep(1);
    }
    __syncthreads();
    if (tid == 0){
      __hip_atomic_store(gen, token, __ATOMIC_RELEASE, SCOPE);
      (void)__hip_atomic_load(gen, __ATOMIC_ACQUIRE, SCOPE);
    }
  } else {
    if (threadIdx.x == 0){
      __hip_atomic_store(flags + bid*32, token, __ATOMIC_RELEASE, SCOPE);
      while (__hip_atomic_load(gen, __ATOMIC_RELAXED, SCOPE) < token)
        __builtin_amdgcn_s_sleep(1);
      (void)__hip_atomic_load(gen, __ATOMIC_ACQUIRE, SCOPE);
    }
  }
  __syncthreads();
}

// ---------------- init ----------------
__global__ __launch_bounds__(256) void k_init(float* __restrict__ ws,
                                              int* __restrict__ inp,
                                              float* __restrict__ loss,
                                              int* __restrict__ bars)
{
  int gid = blockIdx.x*256 + threadIdx.x;        // < 98304
  ws[gid] = 0.f;                                  // cf,cb,c_d,h_d
  if (gid < 81920) ws[262144 + gid] = 0.f;        // h_enc,h_dec,combb
  if (gid < 10304) bars[gid] = 0;                 // flags_e,gen_e,flags_d,gen_d
  if (gid < 32) inp[gid] = SOS_;
  if (gid == 0) *loss = 0.f;
}

// ---------------- one-shot bf16 pre-pack of GEMM B-operands ----------
__global__ __launch_bounds__(256) void k_packall(
    const float* __restrict__ Whh_f, const float* __restrict__ Whh_b,
    const float* __restrict__ W_comb, const float* __restrict__ Wih_d,
    const float* __restrict__ Whh_d, const float* __restrict__ W_out,
    short* __restrict__ pk, long n8)
{
  long gid = (long)blockIdx.x*256 + threadIdx.x;
  if (gid >= n8) return;
  const float* src; short* dst; long idx;
  if      (gid < 131072)  { src = Whh_f;  dst = pk;            idx = gid; }
  else if (gid < 262144)  { src = Whh_b;  dst = pk + 1048576;  idx = gid - 131072; }
  else if (gid < 524288)  { src = W_comb; dst = pk + 2097152;  idx = gid - 262144; }
  else if (gid < 1048576) { src = Wih_d;  dst = pk + 4194304;  idx = gid - 524288; }
  else if (gid < 1572864) { src = Whh_d;  dst = pk + 8388608;  idx = gid - 1048576; }
  else                    { src = W_out;  dst = pk + 12582912; idx = gid - 1572864; }
  ((bf8*)dst)[idx] = fragf(src + idx*8);
}

// ---------------- persistent encoder: 64 blocks, 1 barrier/step ------------
template<bool PKW>
__global__ __launch_bounds__(256, 2) void k_encoder(
    const int* __restrict__ x, const float* __restrict__ emb_enc,
    const float* __restrict__ Wih_f, const float* __restrict__ Wih_b,
    const float* __restrict__ WhhF_f32, const float* __restrict__ WhhB_f32,
    const short* __restrict__ WhhF_bf, const short* __restrict__ WhhB_bf,
    const float* __restrict__ bih_f, const float* __restrict__ bhh_f,
    const float* __restrict__ bih_b, const float* __restrict__ bhh_b,
    float* __restrict__ cf, float* __restrict__ cb,
    short* __restrict__ hbuf,   // [2 bufs][2 dirs][32][512]
    float* __restrict__ EO,
    int* __restrict__ flags, int* __restrict__ gen)
{
  __shared__ __align__(16) float G[64][33];
  const int tid = threadIdx.x, wave = tid >> 6, lane = tid & 63;
  const int q = lane >> 4, col = lane & 15, kq = q*8;
  const int bid = blockIdx.x;
  const int dir = bid >> 5, j0 = (bid & 31) * 16;
  const float* Wih  = dir ? Wih_b    : Wih_f;
  const float* Whhf = dir ? WhhB_f32 : WhhF_f32;
  const short* Whhs = dir ? WhhB_bf  : WhhF_bf;
  const float* bi = dir ? bih_b : bih_f;
  const float* bh = dir ? bhh_b : bhh_f;
  float* C = dir ? cb : cf;
  const int n_glob = wave*512 + j0 + col;
  int tok = 0;

  for (int t = 0; t < L_; ++t){
    const short* hcur = hbuf + (size_t)(((t    & 1)*2 + dir))*16384;
    short*       hnxt = hbuf + (size_t)((((t+1)& 1)*2 + dir))*16384;
    f4 acc0 = {0.f,0.f,0.f,0.f}, acc1 = {0.f,0.f,0.f,0.f};
    { // ih part, K = 0..511
      const float* a0 = emb_enc + (size_t)x[col*L_ + t]*E_ + kq;
      const float* a1 = emb_enc + (size_t)x[(16+col)*L_ + t]*E_ + kq;
      const float* bp = Wih + (size_t)n_glob*512 + kq;
#pragma unroll 4
      for (int i = 0; i < 16; ++i){
        bf8 bb = fragf(bp + i*32);
        acc0 = mfma16(fragf(a0 + i*32), bb, acc0);
        acc1 = mfma16(fragf(a1 + i*32), bb, acc1);
      }
    }
    { // hh part, K = 512..1023
      const short* a0 = hcur + col*512 + kq;
      const short* a1 = hcur + (16+col)*512 + kq;
      const float* bpf = Whhf + (size_t)n_glob*512 + kq;
      const short* bps = Whhs + (size_t)n_glob*512 + kq;
#pragma unroll 4
      for (int i = 0; i < 16; ++i){
        bf8 bb = PKW ? *(const bf8*)(bps + i*32) : fragf(bpf + i*32);
        acc0 = mfma16(*(const bf8*)(a0 + i*32), bb, acc0);
        acc1 = mfma16(*(const bf8*)(a1 + i*32), bb, acc1);
      }
    }
    const int n_loc = wave*16 + col;
#pragma unroll
    for (int r = 0; r < 4; ++r){
      G[n_loc][4*q + r]      = acc0[r];
      G[n_loc][16 + 4*q + r] = acc1[r];
    }
    __syncthreads();
#pragma unroll
    for (int s = 0; s < 2; ++s){
      const int cid = tid + s*256;
      const int b = cid & 31, jj = cid >> 5;
      const int j = j0 + jj;
      float g[4];
#pragma unroll
      for (int gt = 0; gt < 4; ++gt){
        const int n = gt*512 + j;
        g[gt] = G[gt*16 + jj][b] + bi[n] + bh[n];
      }
      float cp = C[b*512 + j];
      float cn = sigf(g[1])*cp + sigf(g[0])*tanh_(g[2]);
      float hn = sigf(g[3])*tanh_(cn);
      C[b*512 + j] = cn;
      hnxt[b*512 + j] = bf1(hn);
      if (b == 0) EO[t*H2_ + dir*512 + j] = hn;   // faithful source-bug broadcast
    }
    gbarf(flags, gen, bid, 64, ++tok);
  }
}

// ---------------- decoder phase helpers ----------------
__device__ __forceinline__ void reduce_body(
    int b, int tid, const float* __restrict__ pmax,
    const float* __restrict__ psum, const int* __restrict__ pidx,
    const float* __restrict__ ptgt, float* __restrict__ loss,
    int* __restrict__ inp, float* SH, int* srow)
{
  float M = -3.4e38f, S = 0.f; int I = 0x7fffffff;
  for (int tl = tid; tl < 500; tl += 256)
    comb3(M, S, I, pmax[tl*32 + b], psum[tl*32 + b], pidx[tl*32 + b]);
#pragma unroll
  for (int msk = 1; msk < 64; msk <<= 1){
    float m2 = __shfl_xor(M, msk), s2 = __shfl_xor(S, msk);
    int i2 = __shfl_xor(I, msk);
    comb3(M, S, I, m2, s2, i2);
  }
  float* sm = SH; float* ss = SH + 8; int* si = (int*)(SH + 16);
  if ((tid & 63) == 0){ sm[tid>>6] = M; ss[tid>>6] = S; si[tid>>6] = I; }
  __syncthreads();
  if (tid == 0){
    M = sm[0]; S = ss[0]; I = si[0];
#pragma unroll
    for (int w = 1; w < 4; ++w) comb3(M, S, I, sm[w], ss[w], si[w]);
    atomicAdd(loss, (M + __logf(S) - ptgt[b]) * (1.0f/32.0f));
    inp[b] = I;
    *srow = I;
  }
}

__device__ __forceinline__ void attn_body(
    int b, int tid, int row,
    const float* __restrict__ emb_dec, const float* __restrict__ h_d,
    const float* __restrict__ W_attn, const float* __restrict__ b_attn,
    const float* __restrict__ EO, float* __restrict__ ctx, float* SH)
{
  float* X = SH; float* sc = SH + 2048; float* red = SH + 2176;
  ((f4*)X)[tid]          = ((const f4*)(emb_dec + (size_t)row*H2_))[tid];
  ((f4*)(X + 1024))[tid] = ((const f4*)(h_d + (size_t)b*H2_))[tid];
  __syncthreads();
  const int lg = tid >> 4, kl = tid & 15;
#pragma unroll
  for (int lr = 0; lr < 8; ++lr){
    const int l = lr*16 + lg;
    const float* w = W_attn + (size_t)l*2048;
    float s = 0.f;
    for (int kk = kl*4; kk < 2048; kk += 64){
      f4 wv = *(const f4*)(w + kk);
      f4 xv = *(const f4*)(X + kk);
      s += wv[0]*xv[0] + wv[1]*xv[1] + wv[2]*xv[2] + wv[3]*xv[3];
    }
#pragma unroll
    for (int msk = 1; msk < 16; msk <<= 1) s += __shfl_xor(s, msk);
    if (kl == 0) sc[l] = s + b_attn[l];
  }
  __syncthreads();
  const float v = sc[tid & 127];
  float m_ = v;
#pragma unroll
  for (int msk = 1; msk < 64; msk <<= 1) m_ = fmaxf(m_, __shfl_xor(m_, msk));
  if ((tid & 63) == 0) red[tid >> 6] = m_;
  __syncthreads();
  const float M = fmaxf(fmaxf(red[0], red[1]), fmaxf(red[2], red[3]));
  const float e_ = __expf(v - M);
  float s_ = e_;
#pragma unroll
  for (int msk = 1; msk < 64; msk <<= 1) s_ += __shfl_xor(s_, msk);
  if ((tid & 63) == 0) red[4 + (tid >> 6)] = s_;
  __syncthreads();
  const float S = red[4] + red[5];
  if (tid < 128) sc[tid] = e_ / S;
  __syncthreads();
  const int d0 = tid*4;
  f4 a = {0.f,0.f,0.f,0.f};
  for (int l = 0; l < 128; ++l){
    const float wgt = sc[l];
    const f4 ev = *(const f4*)(EO + (size_t)l*H2_ + d0);
    a[0] += wgt*ev[0]; a[1] += wgt*ev[1]; a[2] += wgt*ev[2]; a[3] += wgt*ev[3];
  }
  *(f4*)(ctx + (size_t)b*H2_ + d0) = a;
}

// ---------------- persistent decoder: 256 blocks, 4 barriers/step ----------
template<bool PKW, bool PKOUT>
__global__ __launch_bounds__(256, 2) void k_decoder(
    const int* __restrict__ target, const float* __restrict__ emb_dec,
    const float* __restrict__ W_attn, const float* __restrict__ b_attn,
    const float* __restrict__ Wcomb_f32, const short* __restrict__ Wcomb_bf,
    const float* __restrict__ b_comb,
    const float* __restrict__ WihD_f32, const short* __restrict__ WihD_bf,
    const float* __restrict__ WhhD_f32, const short* __restrict__ WhhD_bf,
    const float* __restrict__ bih_d, const float* __restrict__ bhh_d,
    const float* __restrict__ Wout_f32, const short* __restrict__ Wout_bf,
    const float* __restrict__ b_out, const float* __restrict__ EO,
    float* __restrict__ h_d, float* __restrict__ c_d,
    short* __restrict__ hdbuf,    // [2 bufs][32][1024] bf16
    short* __restrict__ combb,    // [32][1024] bf16
    float* __restrict__ ctx,
    float* __restrict__ pmax, float* __restrict__ psum,
    int* __restrict__ pidx, float* __restrict__ ptgt,
    float* __restrict__ loss, int* __restrict__ inp,
    int* __restrict__ flags, int* __restrict__ gen,
    float* __restrict__ out)
{
  __shared__ __align__(16) float SH[2304];
  __shared__ int s_row;
  const int tid = threadIdx.x, wave = tid >> 6, lane = tid & 63;
  const int q = lane >> 4, col = lane & 15, kq = q*8;
  const int bid = blockIdx.x;
  int tok = 0;

  for (int t = 0; t < L_; ++t){
    const short* hcur = hdbuf + (size_t)(t & 1)*32768;
    short*       hnxt = hdbuf + (size_t)((t+1) & 1)*32768;

    // ---- P1 (blocks 0..31): finalize t-1 (nll+argmax) + attention ----
    if (bid < 32){
      if (t > 0)
        reduce_body(bid, tid, pmax, psum, pidx, ptgt, loss, inp, SH, &s_row);
      __syncthreads();
      const int row = (t > 0) ? s_row : inp[bid];
      attn_body(bid, tid, row, emb_dec, h_d, W_attn, b_attn, EO, ctx, SH);
    }
    gbarf(flags, gen, bid, 256, ++tok);

    // ---- P2 (blocks 0..15): comb = relu(concat(e,ctx)@W_comb^T+b) -> bf16 --
    if (bid < 16){
      const int n = bid*64 + wave*16 + col;
      const int r0 = inp[col], r1 = inp[16+col];
      const float* e0 = emb_dec + (size_t)r0*H2_;
      const float* e1 = emb_dec + (size_t)r1*H2_;
      const float* c0 = ctx + col*H2_;
      const float* c1 = ctx + (16+col)*H2_;
      const float* bpf = Wcomb_f32 + (size_t)n*2048;
      const short* bps = Wcomb_bf  + (size_t)n*2048;
      f4 acc0 = {0.f,0.f,0.f,0.f}, acc1 = {0.f,0.f,0.f,0.f};
#pragma unroll 4
      for (int i = 0; i < 32; ++i){
        const int k = i*32 + kq;
        bf8 bb = PKW ? *(const bf8*)(bps + k) : fragf(bpf + k);
        acc0 = mfma16(fragf(e0 + k), bb, acc0);
        acc1 = mfma16(fragf(e1 + k), bb, acc1);
      }
#pragma unroll 4
      for (int i = 0; i < 32; ++i){
        const int k = i*32 + kq;
        bf8 bb = PKW ? *(const bf8*)(bps + 1024 + k) : fragf(bpf + 1024 + k);
        acc0 = mfma16(fragf(c0 + k), bb, acc0);
        acc1 = mfma16(fragf(c1 + k), bb, acc1);
      }
      const float bias = b_comb[n];
#pragma unroll
      for (int r = 0; r < 4; ++r){
        combb[(4*q + r)*H2_ + n]      = bf1(fmaxf(acc0[r] + bias, 0.f));
        combb[(16 + 4*q + r)*H2_ + n] = bf1(fmaxf(acc1[r] + bias, 0.f));
      }
    }
    gbarf(flags, gen, bid, 256, ++tok);

    // ---- P3 (blocks 0..63): LSTM gates GEMM (K=2048) + cell, fused ----
    if (bid < 64){
      const int j0 = bid*16;
      const int n_glob = wave*1024 + j0 + col;   // gate=wave, j=j0+col
      const short* a0c = combb + col*H2_ + kq;
      const short* a1c = combb + (16+col)*H2_ + kq;
      const short* a0h = hcur + col*H2_ + kq;
      const short* a1h = hcur + (16+col)*H2_ + kq;
      const float* bif = WihD_f32 + (size_t)n_glob*H2_ + kq;
      const short* bis = WihD_bf  + (size_t)n_glob*H2_ + kq;
      const float* bhf = WhhD_f32 + (size_t)n_glob*H2_ + kq;
      const short* bhs = WhhD_bf  + (size_t)n_glob*H2_ + kq;
      f4 acc0 = {0.f,0.f,0.f,0.f}, acc1 = {0.f,0.f,0.f,0.f};
#pragma unroll 4
      for (int i = 0; i < 32; ++i){
        bf8 bb = PKW ? *(const bf8*)(bis + i*32) : fragf(bif + i*32);
        acc0 = mfma16(*(const bf8*)(a0c + i*32), bb, acc0);
        acc1 = mfma16(*(const bf8*)(a1c + i*32), bb, acc1);
      }
#pragma unroll 4
      for (int i = 0; i < 32; ++i){
        bf8 bb = PKW ? *(const bf8*)(bhs + i*32) : fragf(bhf + i*32);
        acc0 = mfma16(*(const bf8*)(a0h + i*32), bb, acc0);
        acc1 = mfma16(*(const bf8*)(a1h + i*32), bb, acc1);
      }
      float (*G)[33] = (float(*)[33])SH;
      const int n_loc = wave*16 + col;
#pragma unroll
      for (int r = 0; r < 4; ++r){
        G[n_loc][4*q + r]      = acc0[r];
        G[n_loc][16 + 4*q + r] = acc1[r];
      }
      __syncthreads();
#pragma unroll
      for (int s = 0; s < 2; ++s){
        const int cid = tid + s*256;
        const int b = cid & 31, jj = cid >> 5;
        const int j = j0 + jj;
        float g[4];
#pragma unroll
        for (int gt = 0; gt < 4; ++gt){
          const int n = gt*1024 + j;
          g[gt] = G[gt*16 + jj][b] + bih_d[n] + bhh_d[n];
        }
        float cp = c_d[b*H2_ + j];
        float cn = sigf(g[1])*cp + sigf(g[0])*tanh_(g[2]);
        float hn = sigf(g[3])*tanh_(cn);
        c_d[b*H2_ + j] = cn;
        h_d[b*H2_ + j] = hn;
        hnxt[b*H2_ + j] = bf1(hn);
      }
    }
    gbarf(flags, gen, bid, 256, ++tok);

    // ---- P4 (all blocks): logits GEMM + per-tile online softmax ----
    for (int nt = bid; nt < 500; nt += 256){
      __syncthreads();
      float (*lmax)[32] = (float(*)[32])SH;
      float (*lsum)[32] = (float(*)[32])(SH + 128);
      int   (*lidx)[32] = (int(*)[32])(SH + 256);
      const int n = nt*64 + wave*16 + col;
      const short* a0 = hnxt + col*H2_ + kq;
      const short* a1 = hnxt + (16+col)*H2_ + kq;
      f4 acc[2];
      acc[0] = (f4){0.f,0.f,0.f,0.f};
      acc[1] = (f4){0.f,0.f,0.f,0.f};
      if (PKOUT){
        const short* bp = Wout_bf + (size_t)n*H2_ + kq;
#pragma unroll 8
        for (int i = 0; i < 32; ++i){
          bf8 bb = *(const bf8*)(bp + i*32);
          acc[0] = mfma16(*(const bf8*)(a0 + i*32), bb, acc[0]);
          acc[1] = mfma16(*(const bf8*)(a1 + i*32), bb, acc[1]);
        }
      } else {
        const float* bp = Wout_f32 + (size_t)n*H2_ + kq;
#pragma unroll 4
        for (int i = 0; i < 32; ++i){
          bf8 bb = fragf(bp + i*32);
          acc[0] = mfma16(*(const bf8*)(a0 + i*32), bb, acc[0]);
          acc[1] = mfma16(*(const bf8*)(a1 + i*32), bb, acc[1]);
        }
      }
      const float bias = b_out[n];
#pragma unroll
      for (int mt = 0; mt < 2; ++mt){
        float val[4], mv[4]; int mi[4];
#pragma unroll
        for (int r = 0; r < 4; ++r){
          val[r] = acc[mt][r] + bias;
          int b_ = mt*16 + 4*q + r;
          if (target[b_*L_ + t] == n) ptgt[b_] = val[r];
          mv[r] = val[r]; mi[r] = n;
        }
#pragma unroll
        for (int msk = 1; msk < 16; msk <<= 1){
#pragma unroll
          for (int r = 0; r < 4; ++r){
            float ov = __shfl_xor(mv[r], msk);
            int oi = __shfl_xor(mi[r], msk);
            if (ov > mv[r] || (ov == mv[r] && oi < mi[r])) { mv[r] = ov; mi[r] = oi; }
          }
        }
        float sv[4];
#pragma unroll
        for (int r = 0; r < 4; ++r) sv[r] = __expf(val[r] - mv[r]);
#pragma unroll
        for (int msk = 1; msk < 16; msk <<= 1){
#pragma unroll
          for (int r = 0; r < 4; ++r) sv[r] += __shfl_xor(sv[r], msk);
        }
        if (col == 0){
#pragma unroll
          for (int r = 0; r < 4; ++r){
            int b_ = mt*16 + 4*q + r;
            lmax[wave][b_] = mv[r]; lsum[wave][b_] = sv[r]; lidx[wave][b_] = mi[r];
          }
        }
      }
      __syncthreads();
      if (tid < 32){
        float M = lmax[0][tid], S = lsum[0][tid]; int I = lidx[0][tid];
#pragma unroll
        for (int w = 1; w < 4; ++w)
          comb3(M, S, I, lmax[w][tid], lsum[w][tid], lidx[w][tid]);
        pmax[nt*32 + tid] = M; psum[nt*32 + tid] = S; pidx[nt*32 + tid] = I;
      }
    }
    gbarf(flags, gen, bid, 256, ++tok);
  }

  // final nll/argmax for t = 127, then emit outputs
  if (bid < 32)
    reduce_body(bid, tid, pmax, psum, pidx, ptgt, loss, inp, SH, &s_row);
  gbarf(flags, gen, bid, 256, ++tok);
  if (bid == 0 && tid == 0){
    out[0] = *loss;
    out[1] = *loss * (1.0f/128.0f);
  }
}

// ---------------- host ----------------
extern "C" void kernel_launch(void* const* d_in, const int* in_sizes, int n_in,
                              void* d_out, int out_size, void* d_ws, size_t ws_size,
                              hipStream_t stream)
{
  const int*   x       = (const int*)d_in[0];
  const int*   target  = (const int*)d_in[1];
  const float* emb_enc = (const float*)d_in[4];
  const float* Wih_f   = (const float*)d_in[5];
  const float* Whh_f   = (const float*)d_in[6];
  const float* bih_f   = (const float*)d_in[7];
  const float* bhh_f   = (const float*)d_in[8];
  const float* Wih_b   = (const float*)d_in[9];
  const float* Whh_b   = (const float*)d_in[10];
  const float* bih_b   = (const float*)d_in[11];
  const float* bhh_b   = (const float*)d_in[12];
  const float* emb_dec = (const float*)d_in[13];
  const float* W_attn  = (const float*)d_in[14];
  const float* b_attn  = (const float*)d_in[15];
  const float* W_comb  = (const float*)d_in[16];
  const float* b_comb  = (const float*)d_in[17];
  const float* Wih_d   = (const float*)d_in[18];
  const float* Whh_d   = (const float*)d_in[19];
  const float* bih_d   = (const float*)d_in[20];
  const float* bhh_d   = (const float*)d_in[21];
  const float* W_out   = (const float*)d_in[22];
  const float* b_out   = (const float*)d_in[23];

  float* ws = (float*)d_ws;
  // float-offset layout
  float* cf     = ws + 0;                   // 16384
  float* cb     = ws + 16384;               // 16384
  float* c_d    = ws + 32768;               // 32768
  float* h_d    = ws + 65536;               // 32768
  float* EO     = ws + 98304;               // 131072
  float* ctx    = ws + 229376;              // 32768 -> ends 262144
  short* h_enc  = (short*)(ws + 262144);    // 65536 sh (32768 fl) -> 294912
  short* h_dec  = (short*)(ws + 294912);    // 65536 sh (32768 fl) -> 327680
  short* combb  = (short*)(ws + 327680);    // 32768 sh (16384 fl) -> 344064
  float* pmax   = ws + 344064;              // 16000 -> 360064
  float* psum   = ws + 360064;              // 16000 -> 376064
  int*   pidx   = (int*)(ws + 376064);      // 16000 -> 392064
  float* ptgt   = ws + 392064;              // 32
  float* loss   = ws + 392096;
  int*   inp    = (int*)(ws + 392128);      // 32
  int*   bars   = (int*)(ws + 392160);      // 10304 ints
  int*   flags_e = bars;                    // 64*32
  int*   gen_e   = bars + 2048;             // 32
  int*   flags_d = bars + 2080;             // 256*32
  int*   gen_d   = bars + 10272;            // 32

  // pack region at +8 MiB
  short* pk = (short*)((char*)d_ws + (8u << 20));
  short* WhhF_bf  = pk;
  short* WhhB_bf  = pk + 1048576;
  short* Wcomb_bf = pk + 2097152;
  short* WihD_bf  = pk + 4194304;
  short* WhhD_bf  = pk + 8388608;
  short* Wout_bf  = pk + 12582912;
  const size_t pkw_end   = (size_t)(8u << 20) + 25165824ull;
  const size_t pkout_end = pkw_end + 65536000ull;
  const bool PKW   = (ws_size >= pkw_end);
  const bool PKOUT = (ws_size >= pkout_end);

  k_init<<<384, 256, 0, stream>>>(ws, inp, loss, bars);
  if (PKW){
    const long n8 = PKOUT ? 5668864L : 1572864L;
    const int  gp = (int)((n8 + 255) / 256);
    k_packall<<<gp, 256, 0, stream>>>(Whh_f, Whh_b, W_comb, Wih_d, Whh_d,
                                      W_out, pk, n8);
  }

  if (PKW)
    k_encoder<true><<<64, 256, 0, stream>>>(
        x, emb_enc, Wih_f, Wih_b, Whh_f, Whh_b, WhhF_bf, WhhB_bf,
        bih_f, bhh_f, bih_b, bhh_b, cf, cb, h_enc, EO, flags_e, gen_e);
  else
    k_encoder<false><<<64, 256, 0, stream>>>(
        x, emb_enc, Wih_f, Wih_b, Whh_f, Whh_b, WhhF_bf, WhhB_bf,
        bih_f, bhh_f, bih_b, bhh_b, cf, cb, h_enc, EO, flags_e, gen_e);

  if (PKOUT)
    k_decoder<true, true><<<256, 256, 0, stream>>>(
        target, emb_dec, W_attn, b_attn, W_comb, Wcomb_bf, b_comb,
        Wih_d, WihD_bf, Whh_d, WhhD_bf, bih_d, bhh_d, W_out, Wout_bf, b_out,
        EO, h_d, c_d, h_dec, combb, ctx, pmax, psum, pidx, ptgt,
        loss, inp, flags_d, gen_d, (float*)d_out);
  else if (PKW)
    k_decoder<true, false><<<256, 256, 0, stream>>>(
        target, emb_dec, W_attn, b_attn, W_comb, Wcomb_bf, b_comb,
        Wih_d, WihD_bf, Whh_d, WhhD_bf, bih_d, bhh_d, W_out, Wout_bf, b_out,
        EO, h_d, c_d, h_dec, combb, ctx, pmax, psum, pidx, ptgt,
        loss, inp, flags_d, gen_d, (float*)d_out);
  else
    k_decoder<false, false><<<256, 256, 0, stream>>>(
        target, emb_dec, W_attn, b_attn, W_comb, Wcomb_bf, b_comb,
        Wih_d, WihD_bf, Whh_d, WhhD_bf, bih_d, bhh_d, W_out, Wout_bf, b_out,
        EO, h_d, c_d, h_dec, combb, ctx, pmax, psum, pidx, ptgt,
        loss, inp, flags_d, gen_d, (float*)d_out);
}

// Round 4
// 26197.839 us; speedup vs baseline: 1.1356x; 1.1015x over previous
//
#include <hip/hip_runtime.h>
#include <cstdint>
#include <cstddef>

#define L_ 128
#define B_ 32
#define E_ 512
#define H_ 512
#define H2_ 1024
#define V_ 32000
#define SOS_ 65
#define SCOPE __HIP_MEMORY_SCOPE_AGENT

typedef __attribute__((ext_vector_type(8))) short bf8;
typedef __attribute__((ext_vector_type(4))) float f4;

__device__ __forceinline__ short bf1(float x){
  union { float f; unsigned u; } c; c.f = x;
  return (short)((c.u + 0x8000u) >> 16);
}
__device__ __forceinline__ bf8 fragf(const float* p){
  f4 a = ((const f4*)p)[0], b = ((const f4*)p)[1];
  bf8 r;
  r[0]=bf1(a[0]); r[1]=bf1(a[1]); r[2]=bf1(a[2]); r[3]=bf1(a[3]);
  r[4]=bf1(b[0]); r[5]=bf1(b[1]); r[6]=bf1(b[2]); r[7]=bf1(b[3]);
  return r;
}
__device__ __forceinline__ float sigf(float x){ return 1.0f/(1.0f + __expf(-x)); }
__device__ __forceinline__ float tanh_(float x){ return 1.0f - 2.0f/(__expf(2.0f*x)+1.0f); }
__device__ __forceinline__ f4 mfma16(bf8 a, bf8 b, f4 c){
  return __builtin_amdgcn_mfma_f32_16x16x32_bf16(a, b, c, 0, 0, 0);
}
__device__ __forceinline__ void comb3(float& M, float& S, int& I,
                                      float m2, float s2, int i2){
  if (m2 > M) { S = s2 + S*__expf(M - m2); M = m2; I = i2; }
  else { S += s2*__expf(m2 - M); if (m2 == M && i2 < I) I = i2; }
}

// ---- device-wide flag barrier (proven in r3) ----
__device__ __forceinline__ void gbarf(int* flags, int* gen, int bid,
                                      int nblk, int token){
  __syncthreads();   // drains this block's stores before arrival
  if (bid == 0){
    const int tid = threadIdx.x;
    for (int f = tid; f < nblk; f += blockDim.x){
      if (f >= 1){
        while (__hip_atomic_load(flags + f*32, __ATOMIC_RELAXED, SCOPE) < token)
          __builtin_amdgcn_s_sleep(1);
      }
    }
    __syncthreads();
    if (tid == 0){
      __hip_atomic_store(gen, token, __ATOMIC_RELEASE, SCOPE);
      (void)__hip_atomic_load(gen, __ATOMIC_ACQUIRE, SCOPE);
    }
  } else {
    if (threadIdx.x == 0){
      __hip_atomic_store(flags + bid*32, token, __ATOMIC_RELEASE, SCOPE);
      while (__hip_atomic_load(gen, __ATOMIC_RELAXED, SCOPE) < token)
        __builtin_amdgcn_s_sleep(1);
      (void)__hip_atomic_load(gen, __ATOMIC_ACQUIRE, SCOPE);
    }
  }
  __syncthreads();
}

// ---------------- init ----------------
__global__ __launch_bounds__(256) void k_init(float* __restrict__ ws,
                                              int* __restrict__ inp,
                                              float* __restrict__ loss,
                                              int* __restrict__ bars)
{
  int gid = blockIdx.x*256 + threadIdx.x;        // < 98304
  ws[gid] = 0.f;                                  // cf,cb,c_d,h_d
  if (gid < 81920) ws[262144 + gid] = 0.f;        // h_enc,h_dec,combb
  if (gid < 10304) bars[gid] = 0;                 // flags_e,gen_e,flags_d,gen_d
  if (gid < 32) inp[gid] = SOS_;
  if (gid == 0) *loss = 0.f;
}

// ---------------- one-shot bf16 pre-pack of GEMM B-operands ----------
__global__ __launch_bounds__(256) void k_packall(
    const float* __restrict__ Whh_f, const float* __restrict__ Whh_b,
    const float* __restrict__ W_comb, const float* __restrict__ Wih_d,
    const float* __restrict__ Whh_d, const float* __restrict__ W_out,
    short* __restrict__ pk, long n8)
{
  long gid = (long)blockIdx.x*256 + threadIdx.x;
  if (gid >= n8) return;
  const float* src; short* dst; long idx;
  if      (gid < 131072)  { src = Whh_f;  dst = pk;            idx = gid; }
  else if (gid < 262144)  { src = Whh_b;  dst = pk + 1048576;  idx = gid - 131072; }
  else if (gid < 524288)  { src = W_comb; dst = pk + 2097152;  idx = gid - 262144; }
  else if (gid < 1048576) { src = Wih_d;  dst = pk + 4194304;  idx = gid - 524288; }
  else if (gid < 1572864) { src = Whh_d;  dst = pk + 8388608;  idx = gid - 1048576; }
  else                    { src = W_out;  dst = pk + 12582912; idx = gid - 1572864; }
  ((bf8*)dst)[idx] = fragf(src + idx*8);
}

// ---------------- persistent encoder: 64 blocks x 512 thr, 1 barrier/step --
// waves 0-3: ih half (K=emb 512), waves 4-7: hh half (K=h 512); LDS reduce.
template<bool PKW>
__global__ __launch_bounds__(512, 2) void k_encoder(
    const int* __restrict__ x, const float* __restrict__ emb_enc,
    const float* __restrict__ Wih_f, const float* __restrict__ Wih_b,
    const float* __restrict__ WhhF_f32, const float* __restrict__ WhhB_f32,
    const short* __restrict__ WhhF_bf, const short* __restrict__ WhhB_bf,
    const float* __restrict__ bih_f, const float* __restrict__ bhh_f,
    const float* __restrict__ bih_b, const float* __restrict__ bhh_b,
    float* __restrict__ cf, float* __restrict__ cb,
    short* __restrict__ hbuf,   // [2 bufs][2 dirs][32][512]
    float* __restrict__ EO,
    int* __restrict__ flags, int* __restrict__ gen)
{
  __shared__ __align__(16) float G[2][64][33];
  const int tid = threadIdx.x, wave = tid >> 6, lane = tid & 63;
  const int q = lane >> 4, col = lane & 15, kq = q*8;
  const int half = wave >> 2, hw = wave & 3;
  const int bid = blockIdx.x;
  const int dir = bid >> 5, j0 = (bid & 31) * 16;
  const float* Wih  = dir ? Wih_b    : Wih_f;
  const float* Whhf = dir ? WhhB_f32 : WhhF_f32;
  const short* Whhs = dir ? WhhB_bf  : WhhF_bf;
  const float* bi = dir ? bih_b : bih_f;
  const float* bh = dir ? bhh_b : bhh_f;
  float* C = dir ? cb : cf;
  const int n_glob = hw*512 + j0 + col;   // weight row: gate=hw, j=j0+col
  int tok = 0;

  for (int t = 0; t < L_; ++t){
    const short* hcur = hbuf + (size_t)(((t    & 1)*2 + dir))*16384;
    short*       hnxt = hbuf + (size_t)((((t+1)& 1)*2 + dir))*16384;
    f4 acc0 = {0.f,0.f,0.f,0.f}, acc1 = {0.f,0.f,0.f,0.f};
    if (half == 0){ // ih part, K = 0..511
      const float* a0 = emb_enc + (size_t)x[col*L_ + t]*E_ + kq;
      const float* a1 = emb_enc + (size_t)x[(16+col)*L_ + t]*E_ + kq;
      const float* bp = Wih + (size_t)n_glob*512 + kq;
#pragma unroll 4
      for (int i = 0; i < 16; ++i){
        bf8 bb = fragf(bp + i*32);
        acc0 = mfma16(fragf(a0 + i*32), bb, acc0);
        acc1 = mfma16(fragf(a1 + i*32), bb, acc1);
      }
    } else {        // hh part, K = 512..1023
      const short* a0 = hcur + col*512 + kq;
      const short* a1 = hcur + (16+col)*512 + kq;
      const float* bpf = Whhf + (size_t)n_glob*512 + kq;
      const short* bps = Whhs + (size_t)n_glob*512 + kq;
#pragma unroll 4
      for (int i = 0; i < 16; ++i){
        bf8 bb = PKW ? *(const bf8*)(bps + i*32) : fragf(bpf + i*32);
        acc0 = mfma16(*(const bf8*)(a0 + i*32), bb, acc0);
        acc1 = mfma16(*(const bf8*)(a1 + i*32), bb, acc1);
      }
    }
    const int n_loc = hw*16 + col;
#pragma unroll
    for (int r = 0; r < 4; ++r){
      G[half][n_loc][4*q + r]      = acc0[r];
      G[half][n_loc][16 + 4*q + r] = acc1[r];
    }
    __syncthreads();
    { // cell: 512 threads, one pass over (b, jj)
      const int b = tid & 31, jj = tid >> 5;   // jj 0..15
      const int j = j0 + jj;
      float g[4];
#pragma unroll
      for (int gt = 0; gt < 4; ++gt){
        const int n = gt*512 + j;
        g[gt] = G[0][gt*16 + jj][b] + G[1][gt*16 + jj][b] + bi[n] + bh[n];
      }
      float cp = C[b*512 + j];
      float cn = sigf(g[1])*cp + sigf(g[0])*tanh_(g[2]);
      float hn = sigf(g[3])*tanh_(cn);
      C[b*512 + j] = cn;
      hnxt[b*512 + j] = bf1(hn);
      if (b == 0) EO[t*H2_ + dir*512 + j] = hn;   // faithful source-bug broadcast
    }
    gbarf(flags, gen, bid, 64, ++tok);   // entry sync also guards G reuse
  }
}

// ---------------- decoder phase helpers (512-thread block) ----------------
__device__ __forceinline__ void reduce_body(
    int b, int tid, const float* __restrict__ pmax,
    const float* __restrict__ psum, const int* __restrict__ pidx,
    const float* __restrict__ ptgt, float* __restrict__ loss,
    int* __restrict__ inp, float* SH, int* srow)
{
  // bit-identical association to r3: only first 256 threads carry values
  const bool act = (tid < 256);
  float M = -3.4e38f, S = 0.f; int I = 0x7fffffff;
  if (act){
    for (int tl = tid; tl < 500; tl += 256)
      comb3(M, S, I, pmax[tl*32 + b], psum[tl*32 + b], pidx[tl*32 + b]);
  }
#pragma unroll
  for (int msk = 1; msk < 64; msk <<= 1){
    float m2 = __shfl_xor(M, msk), s2 = __shfl_xor(S, msk);
    int i2 = __shfl_xor(I, msk);
    comb3(M, S, I, m2, s2, i2);
  }
  float* sm = SH; float* ss = SH + 8; int* si = (int*)(SH + 16);
  if ((tid & 63) == 0 && act){ sm[tid>>6] = M; ss[tid>>6] = S; si[tid>>6] = I; }
  __syncthreads();
  if (tid == 0){
    M = sm[0]; S = ss[0]; I = si[0];
#pragma unroll
    for (int w = 1; w < 4; ++w) comb3(M, S, I, sm[w], ss[w], si[w]);
    atomicAdd(loss, (M + __logf(S) - ptgt[b]) * (1.0f/32.0f));
    inp[b] = I;
    *srow = I;
  }
}

__device__ __forceinline__ void attn_body(
    int b, int tid, int row,
    const float* __restrict__ emb_dec, const float* __restrict__ h_d,
    const float* __restrict__ W_attn, const float* __restrict__ b_attn,
    const float* __restrict__ EO, float* __restrict__ ctx, float* SH)
{
  float* X = SH; float* sc = SH + 2048; float* red = SH + 2176;
  if (tid < 256) ((f4*)X)[tid] = ((const f4*)(emb_dec + (size_t)row*H2_))[tid];
  else           ((f4*)X)[tid] = ((const f4*)(h_d + (size_t)b*H2_))[tid - 256];
  __syncthreads();
  const int lg = tid >> 4, kl = tid & 15;   // lg 0..31
#pragma unroll
  for (int lr = 0; lr < 4; ++lr){
    const int l = lr*32 + lg;
    const float* w = W_attn + (size_t)l*2048;
    float s = 0.f;
    for (int kk = kl*4; kk < 2048; kk += 64){
      f4 wv = *(const f4*)(w + kk);
      f4 xv = *(const f4*)(X + kk);
      s += wv[0]*xv[0] + wv[1]*xv[1] + wv[2]*xv[2] + wv[3]*xv[3];
    }
#pragma unroll
    for (int msk = 1; msk < 16; msk <<= 1) s += __shfl_xor(s, msk);
    if (kl == 0) sc[l] = s + b_attn[l];
  }
  __syncthreads();
  const float v = sc[tid & 127];
  float m_ = v;
#pragma unroll
  for (int msk = 1; msk < 64; msk <<= 1) m_ = fmaxf(m_, __shfl_xor(m_, msk));
  if ((tid & 63) == 0) red[tid >> 6] = m_;
  __syncthreads();
  float M = red[0];
#pragma unroll
  for (int w = 1; w < 8; ++w) M = fmaxf(M, red[w]);
  const float e_ = __expf(v - M);
  float s_ = e_;
#pragma unroll
  for (int msk = 1; msk < 64; msk <<= 1) s_ += __shfl_xor(s_, msk);
  if ((tid & 63) == 0) red[8 + (tid >> 6)] = s_;
  __syncthreads();
  const float S = red[8] + red[9];   // waves 0,1 cover scores 0..127 exactly
  if (tid < 128) sc[tid] = e_ / S;
  __syncthreads();
  if (tid < 256){
    const int d0 = tid*4;
    f4 a = {0.f,0.f,0.f,0.f};
    for (int l = 0; l < 128; ++l){
      const float wgt = sc[l];
      const f4 ev = *(const f4*)(EO + (size_t)l*H2_ + d0);
      a[0] += wgt*ev[0]; a[1] += wgt*ev[1]; a[2] += wgt*ev[2]; a[3] += wgt*ev[3];
    }
    *(f4*)(ctx + (size_t)b*H2_ + d0) = a;
  }
}

// ---------------- persistent decoder: 256 blocks x 512 thr, 4 barriers/step
template<bool PKW, bool PKOUT>
__global__ __launch_bounds__(512, 2) void k_decoder(
    const int* __restrict__ target, const float* __restrict__ emb_dec,
    const float* __restrict__ W_attn, const float* __restrict__ b_attn,
    const float* __restrict__ Wcomb_f32, const short* __restrict__ Wcomb_bf,
    const float* __restrict__ b_comb,
    const float* __restrict__ WihD_f32, const short* __restrict__ WihD_bf,
    const float* __restrict__ WhhD_f32, const short* __restrict__ WhhD_bf,
    const float* __restrict__ bih_d, const float* __restrict__ bhh_d,
    const float* __restrict__ Wout_f32, const short* __restrict__ Wout_bf,
    const float* __restrict__ b_out, const float* __restrict__ EO,
    float* __restrict__ h_d, float* __restrict__ c_d,
    short* __restrict__ hdbuf,    // [2 bufs][32][1024] bf16
    short* __restrict__ combb,    // [32][1024] bf16
    float* __restrict__ ctx,
    float* __restrict__ pmax, float* __restrict__ psum,
    int* __restrict__ pidx, float* __restrict__ ptgt,
    float* __restrict__ loss, int* __restrict__ inp,
    int* __restrict__ flags, int* __restrict__ gen,
    float* __restrict__ out)
{
  __shared__ __align__(16) float SH[4352];
  __shared__ int s_row;
  const int tid = threadIdx.x, wave = tid >> 6, lane = tid & 63;
  const int q = lane >> 4, col = lane & 15, kq = q*8;
  const int half = wave >> 2, hw = wave & 3;
  const int bid = blockIdx.x;
  int tok = 0;

  for (int t = 0; t < L_; ++t){
    const short* hcur = hdbuf + (size_t)(t & 1)*32768;
    short*       hnxt = hdbuf + (size_t)((t+1) & 1)*32768;

    // ---- P1 (blocks 0..31): finalize t-1 (nll+argmax) + attention ----
    if (bid < 32){
      if (t > 0)
        reduce_body(bid, tid, pmax, psum, pidx, ptgt, loss, inp, SH, &s_row);
      __syncthreads();
      const int row = (t > 0) ? s_row : inp[bid];
      attn_body(bid, tid, row, emb_dec, h_d, W_attn, b_attn, EO, ctx, SH);
    }
    gbarf(flags, gen, bid, 256, ++tok);

    // ---- P2 (blocks 0..15): comb GEMM, 2-way K-split across wave halves ----
    if (bid < 16){
      const int n = bid*64 + hw*16 + col;
      f4 acc0 = {0.f,0.f,0.f,0.f}, acc1 = {0.f,0.f,0.f,0.f};
      if (half == 0){ // e-part, K 0..1023 of concat
        const int r0 = inp[col], r1 = inp[16+col];
        const float* a0 = emb_dec + (size_t)r0*H2_ + kq;
        const float* a1 = emb_dec + (size_t)r1*H2_ + kq;
        const float* bpf = Wcomb_f32 + (size_t)n*2048 + kq;
        const short* bps = Wcomb_bf  + (size_t)n*2048 + kq;
#pragma unroll 4
        for (int i = 0; i < 32; ++i){
          bf8 bb = PKW ? *(const bf8*)(bps + i*32) : fragf(bpf + i*32);
          acc0 = mfma16(fragf(a0 + i*32), bb, acc0);
          acc1 = mfma16(fragf(a1 + i*32), bb, acc1);
        }
      } else {        // ctx-part, K 1024..2047 of concat
        const float* c0 = ctx + col*H2_ + kq;
        const float* c1 = ctx + (16+col)*H2_ + kq;
        const float* bpf = Wcomb_f32 + (size_t)n*2048 + 1024 + kq;
        const short* bps = Wcomb_bf  + (size_t)n*2048 + 1024 + kq;
#pragma unroll 4
        for (int i = 0; i < 32; ++i){
          bf8 bb = PKW ? *(const bf8*)(bps + i*32) : fragf(bpf + i*32);
          acc0 = mfma16(fragf(c0 + i*32), bb, acc0);
          acc1 = mfma16(fragf(c1 + i*32), bb, acc1);
        }
      }
      float (*G)[64][33] = (float(*)[64][33])SH;
      const int n_loc = hw*16 + col;
#pragma unroll
      for (int r = 0; r < 4; ++r){
        G[half][n_loc][4*q + r]      = acc0[r];
        G[half][n_loc][16 + 4*q + r] = acc1[r];
      }
      __syncthreads();
#pragma unroll
      for (int s2 = 0; s2 < 4; ++s2){
        const int idx = tid + s2*512;       // < 2048 = 64 n x 32 b
        const int nn = idx & 63, b = idx >> 6;
        float s = G[0][nn][b] + G[1][nn][b] + b_comb[bid*64 + nn];
        combb[(size_t)b*H2_ + bid*64 + nn] = bf1(fmaxf(s, 0.f));
      }
    }
    gbarf(flags, gen, bid, 256, ++tok);

    // ---- P3 (blocks 0..63): LSTM gates GEMM, 2-way K-split + cell ----
    if (bid < 64){
      const int j0 = bid*16;
      const int nrow = hw*1024 + j0 + col;   // gate=hw, j=j0+col
      f4 acc0 = {0.f,0.f,0.f,0.f}, acc1 = {0.f,0.f,0.f,0.f};
      if (half == 0){ // comb-input half
        const short* a0 = combb + col*H2_ + kq;
        const short* a1 = combb + (16+col)*H2_ + kq;
        const float* bpf = WihD_f32 + (size_t)nrow*H2_ + kq;
        const short* bps = WihD_bf  + (size_t)nrow*H2_ + kq;
#pragma unroll 4
        for (int i = 0; i < 32; ++i){
          bf8 bb = PKW ? *(const bf8*)(bps + i*32) : fragf(bpf + i*32);
          acc0 = mfma16(*(const bf8*)(a0 + i*32), bb, acc0);
          acc1 = mfma16(*(const bf8*)(a1 + i*32), bb, acc1);
        }
      } else {        // h-input half
        const short* a0 = hcur + col*H2_ + kq;
        const short* a1 = hcur + (16+col)*H2_ + kq;
        const float* bpf = WhhD_f32 + (size_t)nrow*H2_ + kq;
        const short* bps = WhhD_bf  + (size_t)nrow*H2_ + kq;
#pragma unroll 4
        for (int i = 0; i < 32; ++i){
          bf8 bb = PKW ? *(const bf8*)(bps + i*32) : fragf(bpf + i*32);
          acc0 = mfma16(*(const bf8*)(a0 + i*32), bb, acc0);
          acc1 = mfma16(*(const bf8*)(a1 + i*32), bb, acc1);
        }
      }
      float (*G)[64][33] = (float(*)[64][33])SH;
      const int n_loc = hw*16 + col;
#pragma unroll
      for (int r = 0; r < 4; ++r){
        G[half][n_loc][4*q + r]      = acc0[r];
        G[half][n_loc][16 + 4*q + r] = acc1[r];
      }
      __syncthreads();
      { // cell: 512 threads, one pass over (b, jj)
        const int b = tid & 31, jj = tid >> 5;
        const int j = j0 + jj;
        float g[4];
#pragma unroll
        for (int gt = 0; gt < 4; ++gt){
          const int n = gt*1024 + j;
          g[gt] = G[0][gt*16 + jj][b] + G[1][gt*16 + jj][b]
                + bih_d[n] + bhh_d[n];
        }
        float cp = c_d[b*H2_ + j];
        float cn = sigf(g[1])*cp + sigf(g[0])*tanh_(g[2]);
        float hn = sigf(g[3])*tanh_(cn);
        c_d[b*H2_ + j] = cn;
        h_d[b*H2_ + j] = hn;
        hnxt[b*H2_ + j] = bf1(hn);
      }
    }
    gbarf(flags, gen, bid, 256, ++tok);

    // ---- P4 (blocks 0..249): 2 logits tiles/block (waves 0-3 / 4-7) ----
    if (bid < 250){
      const int nt = bid*2 + half;
      const int n = nt*64 + hw*16 + col;
      const short* a0 = hnxt + col*H2_ + kq;
      const short* a1 = hnxt + (16+col)*H2_ + kq;
      f4 acc[2];
      acc[0] = (f4){0.f,0.f,0.f,0.f};
      acc[1] = (f4){0.f,0.f,0.f,0.f};
      if (PKOUT){
        const short* bp = Wout_bf + (size_t)n*H2_ + kq;
#pragma unroll
        for (int h2 = 0; h2 < 2; ++h2){
          bf8 bb[16];
#pragma unroll
          for (int j2 = 0; j2 < 16; ++j2)
            bb[j2] = *(const bf8*)(bp + (h2*16 + j2)*32);
#pragma unroll
          for (int j2 = 0; j2 < 16; ++j2){
            const int i = h2*16 + j2;
            acc[0] = mfma16(*(const bf8*)(a0 + i*32), bb[j2], acc[0]);
            acc[1] = mfma16(*(const bf8*)(a1 + i*32), bb[j2], acc[1]);
          }
        }
      } else {
        const float* bp = Wout_f32 + (size_t)n*H2_ + kq;
#pragma unroll 4
        for (int i = 0; i < 32; ++i){
          bf8 bb = fragf(bp + i*32);
          acc[0] = mfma16(*(const bf8*)(a0 + i*32), bb, acc[0]);
          acc[1] = mfma16(*(const bf8*)(a1 + i*32), bb, acc[1]);
        }
      }
      float (*lmax)[32] = (float(*)[32])SH;          // [8][32]
      float (*lsum)[32] = (float(*)[32])(SH + 256);
      int   (*lidx)[32] = (int(*)[32])(SH + 512);
      const float bias = b_out[n];
#pragma unroll
      for (int mt = 0; mt < 2; ++mt){
        float val[4], mv[4]; int mi[4];
#pragma unroll
        for (int r = 0; r < 4; ++r){
          val[r] = acc[mt][r] + bias;
          int b_ = mt*16 + 4*q + r;
          if (target[b_*L_ + t] == n) ptgt[b_] = val[r];
          mv[r] = val[r]; mi[r] = n;
        }
#pragma unroll
        for (int msk = 1; msk < 16; msk <<= 1){
#pragma unroll
          for (int r = 0; r < 4; ++r){
            float ov = __shfl_xor(mv[r], msk);
            int oi = __shfl_xor(mi[r], msk);
            if (ov > mv[r] || (ov == mv[r] && oi < mi[r])) { mv[r] = ov; mi[r] = oi; }
          }
        }
        float sv[4];
#pragma unroll
        for (int r = 0; r < 4; ++r) sv[r] = __expf(val[r] - mv[r]);
#pragma unroll
        for (int msk = 1; msk < 16; msk <<= 1){
#pragma unroll
          for (int r = 0; r < 4; ++r) sv[r] += __shfl_xor(sv[r], msk);
        }
        if (col == 0){
#pragma unroll
          for (int r = 0; r < 4; ++r){
            int b_ = mt*16 + 4*q + r;
            lmax[wave][b_] = mv[r]; lsum[wave][b_] = sv[r]; lidx[wave][b_] = mi[r];
          }
        }
      }
      __syncthreads();
      if (tid < 64){
        const int hf = tid >> 5, b = tid & 31;
        const int nt2 = bid*2 + hf;
        float M = lmax[hf*4][b], S = lsum[hf*4][b]; int I = lidx[hf*4][b];
#pragma unroll
        for (int w = 1; w < 4; ++w)
          comb3(M, S, I, lmax[hf*4 + w][b], lsum[hf*4 + w][b], lidx[hf*4 + w][b]);
        pmax[nt2*32 + b] = M; psum[nt2*32 + b] = S; pidx[nt2*32 + b] = I;
      }
    }
    gbarf(flags, gen, bid, 256, ++tok);
  }

  // final nll/argmax for t = 127, then emit outputs
  if (bid < 32)
    reduce_body(bid, tid, pmax, psum, pidx, ptgt, loss, inp, SH, &s_row);
  gbarf(flags, gen, bid, 256, ++tok);
  if (bid == 0 && tid == 0){
    out[0] = *loss;
    out[1] = *loss * (1.0f/128.0f);
  }
}

// ---------------- host ----------------
extern "C" void kernel_launch(void* const* d_in, const int* in_sizes, int n_in,
                              void* d_out, int out_size, void* d_ws, size_t ws_size,
                              hipStream_t stream)
{
  const int*   x       = (const int*)d_in[0];
  const int*   target  = (const int*)d_in[1];
  const float* emb_enc = (const float*)d_in[4];
  const float* Wih_f   = (const float*)d_in[5];
  const float* Whh_f   = (const float*)d_in[6];
  const float* bih_f   = (const float*)d_in[7];
  const float* bhh_f   = (const float*)d_in[8];
  const float* Wih_b   = (const float*)d_in[9];
  const float* Whh_b   = (const float*)d_in[10];
  const float* bih_b   = (const float*)d_in[11];
  const float* bhh_b   = (const float*)d_in[12];
  const float* emb_dec = (const float*)d_in[13];
  const float* W_attn  = (const float*)d_in[14];
  const float* b_attn  = (const float*)d_in[15];
  const float* W_comb  = (const float*)d_in[16];
  const float* b_comb  = (const float*)d_in[17];
  const float* Wih_d   = (const float*)d_in[18];
  const float* Whh_d   = (const float*)d_in[19];
  const float* bih_d   = (const float*)d_in[20];
  const float* bhh_d   = (const float*)d_in[21];
  const float* W_out   = (const float*)d_in[22];
  const float* b_out   = (const float*)d_in[23];

  float* ws = (float*)d_ws;
  float* cf     = ws + 0;                   // 16384
  float* cb     = ws + 16384;               // 16384
  float* c_d    = ws + 32768;               // 32768
  float* h_d    = ws + 65536;               // 32768
  float* EO     = ws + 98304;               // 131072
  float* ctx    = ws + 229376;              // 32768 -> 262144
  short* h_enc  = (short*)(ws + 262144);    // 65536 sh -> 294912
  short* h_dec  = (short*)(ws + 294912);    // 65536 sh -> 327680
  short* combb  = (short*)(ws + 327680);    // 32768 sh -> 344064
  float* pmax   = ws + 344064;              // 16000
  float* psum   = ws + 360064;              // 16000
  int*   pidx   = (int*)(ws + 376064);      // 16000
  float* ptgt   = ws + 392064;              // 32
  float* loss   = ws + 392096;
  int*   inp    = (int*)(ws + 392128);      // 32
  int*   bars   = (int*)(ws + 392160);      // 10304 ints
  int*   flags_e = bars;                    // 64*32
  int*   gen_e   = bars + 2048;             // 32
  int*   flags_d = bars + 2080;             // 256*32
  int*   gen_d   = bars + 10272;            // 32

  short* pk = (short*)((char*)d_ws + (8u << 20));
  short* WhhF_bf  = pk;
  short* WhhB_bf  = pk + 1048576;
  short* Wcomb_bf = pk + 2097152;
  short* WihD_bf  = pk + 4194304;
  short* WhhD_bf  = pk + 8388608;
  short* Wout_bf  = pk + 12582912;
  const size_t pkw_end   = (size_t)(8u << 20) + 25165824ull;
  const size_t pkout_end = pkw_end + 65536000ull;
  const bool PKW   = (ws_size >= pkw_end);
  const bool PKOUT = (ws_size >= pkout_end);

  k_init<<<384, 256, 0, stream>>>(ws, inp, loss, bars);
  if (PKW){
    const long n8 = PKOUT ? 5668864L : 1572864L;
    const int  gp = (int)((n8 + 255) / 256);
    k_packall<<<gp, 256, 0, stream>>>(Whh_f, Whh_b, W_comb, Wih_d, Whh_d,
                                      W_out, pk, n8);
  }

  if (PKW)
    k_encoder<true><<<64, 512, 0, stream>>>(
        x, emb_enc, Wih_f, Wih_b, Whh_f, Whh_b, WhhF_bf, WhhB_bf,
        bih_f, bhh_f, bih_b, bhh_b, cf, cb, h_enc, EO, flags_e, gen_e);
  else
    k_encoder<false><<<64, 512, 0, stream>>>(
        x, emb_enc, Wih_f, Wih_b, Whh_f, Whh_b, WhhF_bf, WhhB_bf,
        bih_f, bhh_f, bih_b, bhh_b, cf, cb, h_enc, EO, flags_e, gen_e);

  if (PKOUT)
    k_decoder<true, true><<<256, 512, 0, stream>>>(
        target, emb_dec, W_attn, b_attn, W_comb, Wcomb_bf, b_comb,
        Wih_d, WihD_bf, Whh_d, WhhD_bf, bih_d, bhh_d, W_out, Wout_bf, b_out,
        EO, h_d, c_d, h_dec, combb, ctx, pmax, psum, pidx, ptgt,
        loss, inp, flags_d, gen_d, (float*)d_out);
  else if (PKW)
    k_decoder<true, false><<<256, 512, 0, stream>>>(
        target, emb_dec, W_attn, b_attn, W_comb, Wcomb_bf, b_comb,
        Wih_d, WihD_bf, Whh_d, WhhD_bf, bih_d, bhh_d, W_out, Wout_bf, b_out,
        EO, h_d, c_d, h_dec, combb, ctx, pmax, psum, pidx, ptgt,
        loss, inp, flags_d, gen_d, (float*)d_out);
  else
    k_decoder<false, false><<<256, 512, 0, stream>>>(
        target, emb_dec, W_attn, b_attn, W_comb, Wcomb_bf, b_comb,
        Wih_d, WihD_bf, Whh_d, WhhD_bf, bih_d, bhh_d, W_out, Wout_bf, b_out,
        EO, h_d, c_d, h_dec, combb, ctx, pmax, psum, pidx, ptgt,
        loss, inp, flags_d, gen_d, (float*)d_out);
}

// Round 5
// 18373.505 us; speedup vs baseline: 1.6192x; 1.4258x over previous
//
#include <hip/hip_runtime.h>
#include <cstdint>
#include <cstddef>

#define L_ 128
#define B_ 32
#define E_ 512
#define H_ 512
#define H2_ 1024
#define V_ 32000
#define SOS_ 65
#define SCOPE __HIP_MEMORY_SCOPE_AGENT

typedef __attribute__((ext_vector_type(8))) short bf8;
typedef __attribute__((ext_vector_type(4))) float f4;

__device__ __forceinline__ short bf1(float x){
  union { float f; unsigned u; } c; c.f = x;
  return (short)((c.u + 0x8000u) >> 16);
}
__device__ __forceinline__ bf8 fragf(const float* p){
  f4 a = ((const f4*)p)[0], b = ((const f4*)p)[1];
  bf8 r;
  r[0]=bf1(a[0]); r[1]=bf1(a[1]); r[2]=bf1(a[2]); r[3]=bf1(a[3]);
  r[4]=bf1(b[0]); r[5]=bf1(b[1]); r[6]=bf1(b[2]); r[7]=bf1(b[3]);
  return r;
}
__device__ __forceinline__ float sigf(float x){ return 1.0f/(1.0f + __expf(-x)); }
__device__ __forceinline__ float tanh_(float x){ return 1.0f - 2.0f/(__expf(2.0f*x)+1.0f); }
__device__ __forceinline__ f4 mfma16(bf8 a, bf8 b, f4 c){
  return __builtin_amdgcn_mfma_f32_16x16x32_bf16(a, b, c, 0, 0, 0);
}
__device__ __forceinline__ void comb3(float& M, float& S, int& I,
                                      float m2, float s2, int i2){
  if (m2 > M) { S = s2 + S*__expf(M - m2); M = m2; I = i2; }
  else { S += s2*__expf(m2 - M); if (m2 == M && i2 < I) I = i2; }
}

// ---- device-wide flag barrier (encoder only; proven in r3/r4) ----
__device__ __forceinline__ void gbarf(int* flags, int* gen, int bid,
                                      int nblk, int token){
  __syncthreads();
  if (bid == 0){
    const int tid = threadIdx.x;
    for (int f = tid; f < nblk; f += blockDim.x){
      if (f >= 1){
        while (__hip_atomic_load(flags + f*32, __ATOMIC_RELAXED, SCOPE) < token)
          __builtin_amdgcn_s_sleep(1);
      }
    }
    __syncthreads();
    if (tid == 0){
      __hip_atomic_store(gen, token, __ATOMIC_RELEASE, SCOPE);
      (void)__hip_atomic_load(gen, __ATOMIC_ACQUIRE, SCOPE);
    }
  } else {
    if (threadIdx.x == 0){
      __hip_atomic_store(flags + bid*32, token, __ATOMIC_RELEASE, SCOPE);
      while (__hip_atomic_load(gen, __ATOMIC_RELAXED, SCOPE) < token)
        __builtin_amdgcn_s_sleep(1);
      (void)__hip_atomic_load(gen, __ATOMIC_ACQUIRE, SCOPE);
    }
  }
  __syncthreads();
}

// ---------------- init ----------------
__global__ __launch_bounds__(256) void k_init(float* __restrict__ ws,
                                              int* __restrict__ inp,
                                              float* __restrict__ loss,
                                              int* __restrict__ bars)
{
  int gid = blockIdx.x*256 + threadIdx.x;        // < 98304
  ws[gid] = 0.f;                                  // cf,cb,c_d,h_d
  if (gid < 81920) ws[262144 + gid] = 0.f;        // h_enc,h_dec,combb
  if (gid < 10304) bars[gid] = 0;
  if (gid < 32) inp[gid] = SOS_;
  if (gid == 0) *loss = 0.f;
}

// ---------------- one-shot bf16 pre-pack of GEMM B-operands ----------
__global__ __launch_bounds__(256) void k_packall(
    const float* __restrict__ Whh_f, const float* __restrict__ Whh_b,
    const float* __restrict__ W_comb, const float* __restrict__ Wih_d,
    const float* __restrict__ Whh_d, const float* __restrict__ W_out,
    short* __restrict__ pk, long n8)
{
  long gid = (long)blockIdx.x*256 + threadIdx.x;
  if (gid >= n8) return;
  const float* src; short* dst; long idx;
  if      (gid < 131072)  { src = Whh_f;  dst = pk;            idx = gid; }
  else if (gid < 262144)  { src = Whh_b;  dst = pk + 1048576;  idx = gid - 131072; }
  else if (gid < 524288)  { src = W_comb; dst = pk + 2097152;  idx = gid - 262144; }
  else if (gid < 1048576) { src = Wih_d;  dst = pk + 4194304;  idx = gid - 524288; }
  else if (gid < 1572864) { src = Whh_d;  dst = pk + 8388608;  idx = gid - 1048576; }
  else                    { src = W_out;  dst = pk + 12582912; idx = gid - 1572864; }
  ((bf8*)dst)[idx] = fragf(src + idx*8);
}

// ---------------- persistent encoder (r4 verbatim) ----------------
template<bool PKW>
__global__ __launch_bounds__(512, 2) void k_encoder(
    const int* __restrict__ x, const float* __restrict__ emb_enc,
    const float* __restrict__ Wih_f, const float* __restrict__ Wih_b,
    const float* __restrict__ WhhF_f32, const float* __restrict__ WhhB_f32,
    const short* __restrict__ WhhF_bf, const short* __restrict__ WhhB_bf,
    const float* __restrict__ bih_f, const float* __restrict__ bhh_f,
    const float* __restrict__ bih_b, const float* __restrict__ bhh_b,
    float* __restrict__ cf, float* __restrict__ cb,
    short* __restrict__ hbuf,   // [2 bufs][2 dirs][32][512]
    float* __restrict__ EO,
    int* __restrict__ flags, int* __restrict__ gen)
{
  __shared__ __align__(16) float G[2][64][33];
  const int tid = threadIdx.x, wave = tid >> 6, lane = tid & 63;
  const int q = lane >> 4, col = lane & 15, kq = q*8;
  const int half = wave >> 2, hw = wave & 3;
  const int bid = blockIdx.x;
  const int dir = bid >> 5, j0 = (bid & 31) * 16;
  const float* Wih  = dir ? Wih_b    : Wih_f;
  const float* Whhf = dir ? WhhB_f32 : WhhF_f32;
  const short* Whhs = dir ? WhhB_bf  : WhhF_bf;
  const float* bi = dir ? bih_b : bih_f;
  const float* bh = dir ? bhh_b : bhh_f;
  float* C = dir ? cb : cf;
  const int n_glob = hw*512 + j0 + col;
  int tok = 0;

  for (int t = 0; t < L_; ++t){
    const short* hcur = hbuf + (size_t)(((t    & 1)*2 + dir))*16384;
    short*       hnxt = hbuf + (size_t)((((t+1)& 1)*2 + dir))*16384;
    f4 acc0 = {0.f,0.f,0.f,0.f}, acc1 = {0.f,0.f,0.f,0.f};
    if (half == 0){ // ih part, K = 0..511
      const float* a0 = emb_enc + (size_t)x[col*L_ + t]*E_ + kq;
      const float* a1 = emb_enc + (size_t)x[(16+col)*L_ + t]*E_ + kq;
      const float* bp = Wih + (size_t)n_glob*512 + kq;
#pragma unroll 4
      for (int i = 0; i < 16; ++i){
        bf8 bb = fragf(bp + i*32);
        acc0 = mfma16(fragf(a0 + i*32), bb, acc0);
        acc1 = mfma16(fragf(a1 + i*32), bb, acc1);
      }
    } else {        // hh part, K = 512..1023
      const short* a0 = hcur + col*512 + kq;
      const short* a1 = hcur + (16+col)*512 + kq;
      const float* bpf = Whhf + (size_t)n_glob*512 + kq;
      const short* bps = Whhs + (size_t)n_glob*512 + kq;
#pragma unroll 4
      for (int i = 0; i < 16; ++i){
        bf8 bb = PKW ? *(const bf8*)(bps + i*32) : fragf(bpf + i*32);
        acc0 = mfma16(*(const bf8*)(a0 + i*32), bb, acc0);
        acc1 = mfma16(*(const bf8*)(a1 + i*32), bb, acc1);
      }
    }
    const int n_loc = hw*16 + col;
#pragma unroll
    for (int r = 0; r < 4; ++r){
      G[half][n_loc][4*q + r]      = acc0[r];
      G[half][n_loc][16 + 4*q + r] = acc1[r];
    }
    __syncthreads();
    {
      const int b = tid & 31, jj = tid >> 5;
      const int j = j0 + jj;
      float g[4];
#pragma unroll
      for (int gt = 0; gt < 4; ++gt){
        const int n = gt*512 + j;
        g[gt] = G[0][gt*16 + jj][b] + G[1][gt*16 + jj][b] + bi[n] + bh[n];
      }
      float cp = C[b*512 + j];
      float cn = sigf(g[1])*cp + sigf(g[0])*tanh_(g[2]);
      float hn = sigf(g[3])*tanh_(cn);
      C[b*512 + j] = cn;
      hnxt[b*512 + j] = bf1(hn);
      if (b == 0) EO[t*H2_ + dir*512 + j] = hn;
    }
    gbarf(flags, gen, bid, 64, ++tok);
  }
}

// ---------------- decoder phase helpers (512-thread, r4 verbatim) ---------
__device__ __forceinline__ void reduce_body(
    int b, int tid, const float* __restrict__ pmax,
    const float* __restrict__ psum, const int* __restrict__ pidx,
    const float* __restrict__ ptgt, float* __restrict__ loss,
    int* __restrict__ inp, float* SH, int* srow)
{
  const bool act = (tid < 256);
  float M = -3.4e38f, S = 0.f; int I = 0x7fffffff;
  if (act){
    for (int tl = tid; tl < 500; tl += 256)
      comb3(M, S, I, pmax[tl*32 + b], psum[tl*32 + b], pidx[tl*32 + b]);
  }
#pragma unroll
  for (int msk = 1; msk < 64; msk <<= 1){
    float m2 = __shfl_xor(M, msk), s2 = __shfl_xor(S, msk);
    int i2 = __shfl_xor(I, msk);
    comb3(M, S, I, m2, s2, i2);
  }
  float* sm = SH; float* ss = SH + 8; int* si = (int*)(SH + 16);
  if ((tid & 63) == 0 && act){ sm[tid>>6] = M; ss[tid>>6] = S; si[tid>>6] = I; }
  __syncthreads();
  if (tid == 0){
    M = sm[0]; S = ss[0]; I = si[0];
#pragma unroll
    for (int w = 1; w < 4; ++w) comb3(M, S, I, sm[w], ss[w], si[w]);
    atomicAdd(loss, (M + __logf(S) - ptgt[b]) * (1.0f/32.0f));
    inp[b] = I;
    *srow = I;
  }
}

__device__ __forceinline__ void attn_body(
    int b, int tid, int row,
    const float* __restrict__ emb_dec, const float* __restrict__ h_d,
    const float* __restrict__ W_attn, const float* __restrict__ b_attn,
    const float* __restrict__ EO, float* __restrict__ ctx, float* SH)
{
  float* X = SH; float* sc = SH + 2048; float* red = SH + 2176;
  if (tid < 256) ((f4*)X)[tid] = ((const f4*)(emb_dec + (size_t)row*H2_))[tid];
  else           ((f4*)X)[tid] = ((const f4*)(h_d + (size_t)b*H2_))[tid - 256];
  __syncthreads();
  const int lg = tid >> 4, kl = tid & 15;
#pragma unroll
  for (int lr = 0; lr < 4; ++lr){
    const int l = lr*32 + lg;
    const float* w = W_attn + (size_t)l*2048;
    float s = 0.f;
    for (int kk = kl*4; kk < 2048; kk += 64){
      f4 wv = *(const f4*)(w + kk);
      f4 xv = *(const f4*)(X + kk);
      s += wv[0]*xv[0] + wv[1]*xv[1] + wv[2]*xv[2] + wv[3]*xv[3];
    }
#pragma unroll
    for (int msk = 1; msk < 16; msk <<= 1) s += __shfl_xor(s, msk);
    if (kl == 0) sc[l] = s + b_attn[l];
  }
  __syncthreads();
  const float v = sc[tid & 127];
  float m_ = v;
#pragma unroll
  for (int msk = 1; msk < 64; msk <<= 1) m_ = fmaxf(m_, __shfl_xor(m_, msk));
  if ((tid & 63) == 0) red[tid >> 6] = m_;
  __syncthreads();
  float M = red[0];
#pragma unroll
  for (int w = 1; w < 8; ++w) M = fmaxf(M, red[w]);
  const float e_ = __expf(v - M);
  float s_ = e_;
#pragma unroll
  for (int msk = 1; msk < 64; msk <<= 1) s_ += __shfl_xor(s_, msk);
  if ((tid & 63) == 0) red[8 + (tid >> 6)] = s_;
  __syncthreads();
  const float S = red[8] + red[9];
  if (tid < 128) sc[tid] = e_ / S;
  __syncthreads();
  if (tid < 256){
    const int d0 = tid*4;
    f4 a = {0.f,0.f,0.f,0.f};
    for (int l = 0; l < 128; ++l){
      const float wgt = sc[l];
      const f4 ev = *(const f4*)(EO + (size_t)l*H2_ + d0);
      a[0] += wgt*ev[0]; a[1] += wgt*ev[1]; a[2] += wgt*ev[2]; a[3] += wgt*ev[3];
    }
    *(f4*)(ctx + (size_t)b*H2_ + d0) = a;
  }
}

// ---------------- P1: reduce(t-1) + attention (32 blocks x 512) ------------
__global__ __launch_bounds__(512, 2) void k_p1(
    int t, const float* __restrict__ emb_dec,
    const float* __restrict__ W_attn, const float* __restrict__ b_attn,
    const float* __restrict__ EO, float* __restrict__ h_d,
    float* __restrict__ ctx,
    const float* __restrict__ pmax, const float* __restrict__ psum,
    const int* __restrict__ pidx, const float* __restrict__ ptgt,
    float* __restrict__ loss, int* __restrict__ inp)
{
  __shared__ __align__(16) float SH[2304];
  __shared__ int s_row;
  const int tid = threadIdx.x, bid = blockIdx.x;
  if (t > 0)
    reduce_body(bid, tid, pmax, psum, pidx, ptgt, loss, inp, SH, &s_row);
  __syncthreads();
  const int row = (t > 0) ? s_row : inp[bid];
  attn_body(bid, tid, row, emb_dec, h_d, W_attn, b_attn, EO, ctx, SH);
}

// ---------------- P2: comb GEMM (64 blocks x 128, 2-way K-split) -----------
// Same association as r4's P2 (wave half 0 = e-part, half 1 = ctx-part).
template<bool PKW>
__global__ __launch_bounds__(128, 4) void k_comb(
    const int* __restrict__ inp, const float* __restrict__ emb_dec,
    const float* __restrict__ ctx,
    const float* __restrict__ Wcomb_f32, const short* __restrict__ Wcomb_bf,
    const float* __restrict__ b_comb, short* __restrict__ combb)
{
  __shared__ __align__(16) float G[2][16][33];
  const int tid = threadIdx.x, half = tid >> 6, lane = tid & 63;
  const int q = lane >> 4, col = lane & 15, kq = q*8;
  const int bid = blockIdx.x;
  const int n = bid*16 + col;
  f4 acc0 = {0.f,0.f,0.f,0.f}, acc1 = {0.f,0.f,0.f,0.f};
  if (half == 0){ // e-part, K 0..1023
    const int r0 = inp[col], r1 = inp[16+col];
    const float* a0 = emb_dec + (size_t)r0*H2_ + kq;
    const float* a1 = emb_dec + (size_t)r1*H2_ + kq;
    const float* bpf = Wcomb_f32 + (size_t)n*2048 + kq;
    const short* bps = Wcomb_bf  + (size_t)n*2048 + kq;
#pragma unroll 4
    for (int i = 0; i < 32; ++i){
      bf8 bb = PKW ? *(const bf8*)(bps + i*32) : fragf(bpf + i*32);
      acc0 = mfma16(fragf(a0 + i*32), bb, acc0);
      acc1 = mfma16(fragf(a1 + i*32), bb, acc1);
    }
  } else {        // ctx-part, K 1024..2047
    const float* c0 = ctx + col*H2_ + kq;
    const float* c1 = ctx + (16+col)*H2_ + kq;
    const float* bpf = Wcomb_f32 + (size_t)n*2048 + 1024 + kq;
    const short* bps = Wcomb_bf  + (size_t)n*2048 + 1024 + kq;
#pragma unroll 4
    for (int i = 0; i < 32; ++i){
      bf8 bb = PKW ? *(const bf8*)(bps + i*32) : fragf(bpf + i*32);
      acc0 = mfma16(fragf(c0 + i*32), bb, acc0);
      acc1 = mfma16(fragf(c1 + i*32), bb, acc1);
    }
  }
#pragma unroll
  for (int r = 0; r < 4; ++r){
    G[half][col][4*q + r]      = acc0[r];
    G[half][col][16 + 4*q + r] = acc1[r];
  }
  __syncthreads();
#pragma unroll
  for (int s2 = 0; s2 < 4; ++s2){
    const int idx = tid + s2*128;       // < 512 = 16 n x 32 b
    const int nn = idx & 15, b = idx >> 4;
    float s = G[0][nn][b] + G[1][nn][b] + b_comb[bid*16 + nn];
    combb[(size_t)b*H2_ + bid*16 + nn] = bf1(fmaxf(s, 0.f));
  }
}

// ---------------- P3: LSTM gates GEMM + cell (64 blocks x 512) -------------
template<bool PKW>
__global__ __launch_bounds__(512, 2) void k_gates(
    int t, const short* __restrict__ combb,
    const float* __restrict__ WihD_f32, const short* __restrict__ WihD_bf,
    const float* __restrict__ WhhD_f32, const short* __restrict__ WhhD_bf,
    const float* __restrict__ bih_d, const float* __restrict__ bhh_d,
    float* __restrict__ h_d, float* __restrict__ c_d,
    short* __restrict__ hdbuf)
{
  __shared__ __align__(16) float G[2][64][33];
  const int tid = threadIdx.x, wave = tid >> 6, lane = tid & 63;
  const int q = lane >> 4, col = lane & 15, kq = q*8;
  const int half = wave >> 2, hw = wave & 3;
  const int bid = blockIdx.x;
  const short* hcur = hdbuf + (size_t)(t & 1)*32768;
  short*       hnxt = hdbuf + (size_t)((t+1) & 1)*32768;
  const int j0 = bid*16;
  const int nrow = hw*1024 + j0 + col;
  f4 acc0 = {0.f,0.f,0.f,0.f}, acc1 = {0.f,0.f,0.f,0.f};
  if (half == 0){ // comb-input half
    const short* a0 = combb + col*H2_ + kq;
    const short* a1 = combb + (16+col)*H2_ + kq;
    const float* bpf = WihD_f32 + (size_t)nrow*H2_ + kq;
    const short* bps = WihD_bf  + (size_t)nrow*H2_ + kq;
#pragma unroll 4
    for (int i = 0; i < 32; ++i){
      bf8 bb = PKW ? *(const bf8*)(bps + i*32) : fragf(bpf + i*32);
      acc0 = mfma16(*(const bf8*)(a0 + i*32), bb, acc0);
      acc1 = mfma16(*(const bf8*)(a1 + i*32), bb, acc1);
    }
  } else {        // h-input half
    const short* a0 = hcur + col*H2_ + kq;
    const short* a1 = hcur + (16+col)*H2_ + kq;
    const float* bpf = WhhD_f32 + (size_t)nrow*H2_ + kq;
    const short* bps = WhhD_bf  + (size_t)nrow*H2_ + kq;
#pragma unroll 4
    for (int i = 0; i < 32; ++i){
      bf8 bb = PKW ? *(const bf8*)(bps + i*32) : fragf(bpf + i*32);
      acc0 = mfma16(*(const bf8*)(a0 + i*32), bb, acc0);
      acc1 = mfma16(*(const bf8*)(a1 + i*32), bb, acc1);
    }
  }
  const int n_loc = hw*16 + col;
#pragma unroll
  for (int r = 0; r < 4; ++r){
    G[half][n_loc][4*q + r]      = acc0[r];
    G[half][n_loc][16 + 4*q + r] = acc1[r];
  }
  __syncthreads();
  {
    const int b = tid & 31, jj = tid >> 5;
    const int j = j0 + jj;
    float g[4];
#pragma unroll
    for (int gt = 0; gt < 4; ++gt){
      const int n = gt*1024 + j;
      g[gt] = G[0][gt*16 + jj][b] + G[1][gt*16 + jj][b]
            + bih_d[n] + bhh_d[n];
    }
    float cp = c_d[b*H2_ + j];
    float cn = sigf(g[1])*cp + sigf(g[0])*tanh_(g[2]);
    float hn = sigf(g[3])*tanh_(cn);
    c_d[b*H2_ + j] = cn;
    h_d[b*H2_ + j] = hn;
    hnxt[b*H2_ + j] = bf1(hn);
  }
}

// ---------------- P4: logits GEMM + per-tile softmax (500 blocks x 256) ----
template<bool PKOUT>
__global__ __launch_bounds__(256) void k_logits(
    int t, const short* __restrict__ hdbuf,
    const float* __restrict__ Wout_f32, const short* __restrict__ Wout_bf,
    const float* __restrict__ b_out, const int* __restrict__ target,
    float* __restrict__ pmax, float* __restrict__ psum,
    int* __restrict__ pidx, float* __restrict__ ptgt)
{
  __shared__ float lmax[4][32], lsum[4][32];
  __shared__ int lidx[4][32];
  const int tid = threadIdx.x, wave = tid >> 6, lane = tid & 63;
  const int q = lane >> 4, col = lane & 15, kq = q*8;
  const int nt = blockIdx.x;
  const int n = nt*64 + wave*16 + col;
  const short* hnxt = hdbuf + (size_t)((t+1) & 1)*32768;
  const short* a0 = hnxt + col*H2_ + kq;
  const short* a1 = hnxt + (16+col)*H2_ + kq;
  f4 acc[2];
  acc[0] = (f4){0.f,0.f,0.f,0.f};
  acc[1] = (f4){0.f,0.f,0.f,0.f};
  if (PKOUT){
    const short* bp = Wout_bf + (size_t)n*H2_ + kq;
    bf8 bb[32];
#pragma unroll
    for (int i = 0; i < 32; ++i)
      bb[i] = *(const bf8*)(bp + i*32);
#pragma unroll
    for (int i = 0; i < 32; ++i){
      acc[0] = mfma16(*(const bf8*)(a0 + i*32), bb[i], acc[0]);
      acc[1] = mfma16(*(const bf8*)(a1 + i*32), bb[i], acc[1]);
    }
  } else {
    const float* bp = Wout_f32 + (size_t)n*H2_ + kq;
#pragma unroll 4
    for (int i = 0; i < 32; ++i){
      bf8 bb = fragf(bp + i*32);
      acc[0] = mfma16(*(const bf8*)(a0 + i*32), bb, acc[0]);
      acc[1] = mfma16(*(const bf8*)(a1 + i*32), bb, acc[1]);
    }
  }
  const float bias = b_out[n];
#pragma unroll
  for (int mt = 0; mt < 2; ++mt){
    float val[4], mv[4]; int mi[4];
#pragma unroll
    for (int r = 0; r < 4; ++r){
      val[r] = acc[mt][r] + bias;
      int b_ = mt*16 + 4*q + r;
      if (target[b_*L_ + t] == n) ptgt[b_] = val[r];
      mv[r] = val[r]; mi[r] = n;
    }
#pragma unroll
    for (int msk = 1; msk < 16; msk <<= 1){
#pragma unroll
      for (int r = 0; r < 4; ++r){
        float ov = __shfl_xor(mv[r], msk);
        int oi = __shfl_xor(mi[r], msk);
        if (ov > mv[r] || (ov == mv[r] && oi < mi[r])) { mv[r] = ov; mi[r] = oi; }
      }
    }
    float sv[4];
#pragma unroll
    for (int r = 0; r < 4; ++r) sv[r] = __expf(val[r] - mv[r]);
#pragma unroll
    for (int msk = 1; msk < 16; msk <<= 1){
#pragma unroll
      for (int r = 0; r < 4; ++r) sv[r] += __shfl_xor(sv[r], msk);
    }
    if (col == 0){
#pragma unroll
      for (int r = 0; r < 4; ++r){
        int b_ = mt*16 + 4*q + r;
        lmax[wave][b_] = mv[r]; lsum[wave][b_] = sv[r]; lidx[wave][b_] = mi[r];
      }
    }
  }
  __syncthreads();
  if (tid < 32){
    float M = lmax[0][tid], S = lsum[0][tid]; int I = lidx[0][tid];
#pragma unroll
    for (int w = 1; w < 4; ++w)
      comb3(M, S, I, lmax[w][tid], lsum[w][tid], lidx[w][tid]);
    pmax[nt*32 + tid] = M; psum[nt*32 + tid] = S; pidx[nt*32 + tid] = I;
  }
}

// ---------------- final reduce (t=127) + output ----------------
__global__ __launch_bounds__(512) void k_fin(
    const float* __restrict__ pmax, const float* __restrict__ psum,
    const int* __restrict__ pidx, const float* __restrict__ ptgt,
    float* __restrict__ loss, int* __restrict__ inp)
{
  __shared__ __align__(16) float SH[2304];
  __shared__ int s_row;
  reduce_body(blockIdx.x, threadIdx.x, pmax, psum, pidx, ptgt, loss, inp,
              SH, &s_row);
}

__global__ void k_final(const float* __restrict__ loss, float* __restrict__ out)
{
  out[0] = *loss;
  out[1] = *loss * (1.0f/128.0f);
}

// ---------------- host ----------------
extern "C" void kernel_launch(void* const* d_in, const int* in_sizes, int n_in,
                              void* d_out, int out_size, void* d_ws, size_t ws_size,
                              hipStream_t stream)
{
  const int*   x       = (const int*)d_in[0];
  const int*   target  = (const int*)d_in[1];
  const float* emb_enc = (const float*)d_in[4];
  const float* Wih_f   = (const float*)d_in[5];
  const float* Whh_f   = (const float*)d_in[6];
  const float* bih_f   = (const float*)d_in[7];
  const float* bhh_f   = (const float*)d_in[8];
  const float* Wih_b   = (const float*)d_in[9];
  const float* Whh_b   = (const float*)d_in[10];
  const float* bih_b   = (const float*)d_in[11];
  const float* bhh_b   = (const float*)d_in[12];
  const float* emb_dec = (const float*)d_in[13];
  const float* W_attn  = (const float*)d_in[14];
  const float* b_attn  = (const float*)d_in[15];
  const float* W_comb  = (const float*)d_in[16];
  const float* b_comb  = (const float*)d_in[17];
  const float* Wih_d   = (const float*)d_in[18];
  const float* Whh_d   = (const float*)d_in[19];
  const float* bih_d   = (const float*)d_in[20];
  const float* bhh_d   = (const float*)d_in[21];
  const float* W_out   = (const float*)d_in[22];
  const float* b_out   = (const float*)d_in[23];

  float* ws = (float*)d_ws;
  float* cf     = ws + 0;                   // 16384
  float* cb     = ws + 16384;               // 16384
  float* c_d    = ws + 32768;               // 32768
  float* h_d    = ws + 65536;               // 32768
  float* EO     = ws + 98304;               // 131072
  float* ctx    = ws + 229376;              // 32768 -> 262144
  short* h_enc  = (short*)(ws + 262144);    // 65536 sh -> 294912
  short* h_dec  = (short*)(ws + 294912);    // 65536 sh -> 327680
  short* combb  = (short*)(ws + 327680);    // 32768 sh -> 344064
  float* pmax   = ws + 344064;              // 16000
  float* psum   = ws + 360064;              // 16000
  int*   pidx   = (int*)(ws + 376064);      // 16000
  float* ptgt   = ws + 392064;              // 32
  float* loss   = ws + 392096;
  int*   inp    = (int*)(ws + 392128);      // 32
  int*   bars   = (int*)(ws + 392160);      // 10304 ints
  int*   flags_e = bars;                    // 64*32
  int*   gen_e   = bars + 2048;             // 32

  short* pk = (short*)((char*)d_ws + (8u << 20));
  short* WhhF_bf  = pk;
  short* WhhB_bf  = pk + 1048576;
  short* Wcomb_bf = pk + 2097152;
  short* WihD_bf  = pk + 4194304;
  short* WhhD_bf  = pk + 8388608;
  short* Wout_bf  = pk + 12582912;
  const size_t pkw_end   = (size_t)(8u << 20) + 25165824ull;
  const size_t pkout_end = pkw_end + 65536000ull;
  const bool PKW   = (ws_size >= pkw_end);
  const bool PKOUT = (ws_size >= pkout_end);

  k_init<<<384, 256, 0, stream>>>(ws, inp, loss, bars);
  if (PKW){
    const long n8 = PKOUT ? 5668864L : 1572864L;
    const int  gp = (int)((n8 + 255) / 256);
    k_packall<<<gp, 256, 0, stream>>>(Whh_f, Whh_b, W_comb, Wih_d, Whh_d,
                                      W_out, pk, n8);
  }

  if (PKW)
    k_encoder<true><<<64, 512, 0, stream>>>(
        x, emb_enc, Wih_f, Wih_b, Whh_f, Whh_b, WhhF_bf, WhhB_bf,
        bih_f, bhh_f, bih_b, bhh_b, cf, cb, h_enc, EO, flags_e, gen_e);
  else
    k_encoder<false><<<64, 512, 0, stream>>>(
        x, emb_enc, Wih_f, Wih_b, Whh_f, Whh_b, WhhF_bf, WhhB_bf,
        bih_f, bhh_f, bih_b, bhh_b, cf, cb, h_enc, EO, flags_e, gen_e);

  for (int t = 0; t < L_; ++t){
    k_p1<<<32, 512, 0, stream>>>(t, emb_dec, W_attn, b_attn, EO, h_d, ctx,
                                 pmax, psum, pidx, ptgt, loss, inp);
    if (PKW){
      k_comb<true><<<64, 128, 0, stream>>>(inp, emb_dec, ctx, W_comb,
                                           Wcomb_bf, b_comb, combb);
      k_gates<true><<<64, 512, 0, stream>>>(t, combb, Wih_d, WihD_bf,
                                            Whh_d, WhhD_bf, bih_d, bhh_d,
                                            h_d, c_d, h_dec);
    } else {
      k_comb<false><<<64, 128, 0, stream>>>(inp, emb_dec, ctx, W_comb,
                                            Wcomb_bf, b_comb, combb);
      k_gates<false><<<64, 512, 0, stream>>>(t, combb, Wih_d, WihD_bf,
                                             Whh_d, WhhD_bf, bih_d, bhh_d,
                                             h_d, c_d, h_dec);
    }
    if (PKOUT)
      k_logits<true><<<500, 256, 0, stream>>>(t, h_dec, W_out, Wout_bf,
                                              b_out, target, pmax, psum,
                                              pidx, ptgt);
    else
      k_logits<false><<<500, 256, 0, stream>>>(t, h_dec, W_out, Wout_bf,
                                               b_out, target, pmax, psum,
                                               pidx, ptgt);
  }
  k_fin<<<32, 512, 0, stream>>>(pmax, psum, pidx, ptgt, loss, inp);
  k_final<<<1, 1, 0, stream>>>(loss, (float*)d_out);
}